// Round 1
// baseline (1499.698 us; speedup 1.0000x reference)
//
#include <hip/hip_runtime.h>

#define L_SEQ 4096
#define DM 128
#define DIN 256

// ---------------- K1: ConvTranspose2d(2x2,s2) + bias + concat -> seq (B,L,128)
__global__ __launch_bounds__(256) void upcat_kernel(
    const float* __restrict__ x, const float* __restrict__ skip,
    const float* __restrict__ up_w, const float* __restrict__ up_b,
    float* __restrict__ seq) {
  int b = blockIdx.x >> 6, hh = blockIdx.x & 63;
  int h = hh >> 1, i = hh & 1;
  int tid = threadIdx.x;
  __shared__ float xs[128 * 32];     // x[b][c][h][:]
  __shared__ float wsh[128 * 128];   // w[c][o*2+j] for this i
  for (int e = tid; e < 128 * 32; e += 256) {
    int c = e >> 5, w = e & 31;
    xs[e] = x[(((size_t)b * 128 + c) * 32 + h) * 32 + w];
  }
  for (int e = tid; e < 128 * 128; e += 256) {
    int c = e >> 7, oj = e & 127;
    int o = oj >> 1, j = oj & 1;
    wsh[e] = up_w[c * 256 + o * 4 + i * 2 + j];
  }
  __syncthreads();
  int o = tid & 63, wq = tid >> 6;
  float bias = up_b[o];
  size_t mrow_base = (size_t)b * L_SEQ + (size_t)hh * 64;
  for (int s = 0; s < 16; ++s) {
    int ww = wq * 16 + s;
    int w = ww >> 1, j = ww & 1;
    float acc = bias;
#pragma unroll 8
    for (int c = 0; c < 128; ++c)
      acc = fmaf(xs[c * 32 + w], wsh[c * 128 + o * 2 + j], acc);
    seq[(mrow_base + ww) * DM + o] = acc;
  }
  // skip half: channels 64..127
  for (int e = tid; e < 4096; e += 256) {
    int c = e & 63, ww = e >> 6;
    seq[(mrow_base + ww) * DM + 64 + c] =
        skip[((size_t)b * 64 + c) * (size_t)L_SEQ + hh * 64 + ww];
  }
}

// ---------------- generic fp32 GEMM: C[M][N] = A[M][K] @ W[N][K]^T
__global__ __launch_bounds__(256) void gemm_bt(
    const float* __restrict__ A, const float* __restrict__ W,
    float* __restrict__ C, int M, int N, int K) {
  __shared__ float As[32][68];  // [k][m], pad 68
  __shared__ float Ws[32][68];  // [k][n]
  int m0 = blockIdx.x * 64, n0 = blockIdx.y * 64;
  int tid = threadIdx.x;
  int tx = tid & 15, ty = tid >> 4;
  float acc[4][4];
#pragma unroll
  for (int a = 0; a < 4; ++a)
#pragma unroll
    for (int bb = 0; bb < 4; ++bb) acc[a][bb] = 0.f;

  for (int k0 = 0; k0 < K; k0 += 32) {
    __syncthreads();
    for (int e = tid; e < 512; e += 256) {
      int r = e >> 3;
      int c4 = (e & 7) << 2;
      float4 va = *(const float4*)(A + (size_t)(m0 + r) * K + k0 + c4);
      As[c4 + 0][r] = va.x; As[c4 + 1][r] = va.y;
      As[c4 + 2][r] = va.z; As[c4 + 3][r] = va.w;
      float4 vw = *(const float4*)(W + (size_t)(n0 + r) * K + k0 + c4);
      Ws[c4 + 0][r] = vw.x; Ws[c4 + 1][r] = vw.y;
      Ws[c4 + 2][r] = vw.z; Ws[c4 + 3][r] = vw.w;
    }
    __syncthreads();
#pragma unroll
    for (int kk = 0; kk < 32; ++kk) {
      float4 av = *(const float4*)(&As[kk][ty * 4]);
      float4 wv = *(const float4*)(&Ws[kk][tx * 4]);
      float av_[4] = {av.x, av.y, av.z, av.w};
      float wv_[4] = {wv.x, wv.y, wv.z, wv.w};
#pragma unroll
      for (int a = 0; a < 4; ++a)
#pragma unroll
        for (int bb = 0; bb < 4; ++bb)
          acc[a][bb] = fmaf(av_[a], wv_[bb], acc[a][bb]);
    }
  }
#pragma unroll
  for (int a = 0; a < 4; ++a)
#pragma unroll
    for (int bb = 0; bb < 4; ++bb)
      C[(size_t)(m0 + ty * 4 + a) * N + n0 + tx * 4 + bb] = acc[a][bb];
}

// ---------------- K3: depthwise causal conv1d + bias + silu -> u (B,L,256)
__global__ __launch_bounds__(256) void conv_silu_kernel(
    const float* __restrict__ xz, const float* __restrict__ cw,
    const float* __restrict__ cb, float* __restrict__ u) {
  int idx = blockIdx.x * 256 + threadIdx.x;   // over B*L*256
  int d = idx & 255;
  int m = idx >> 8;
  int l = m & (L_SEQ - 1);
  float acc = cb[d];
#pragma unroll
  for (int t = 0; t < 4; ++t) {
    int ls = l - 3 + t;
    if (ls >= 0)
      acc = fmaf(xz[(size_t)(m - 3 + t) * 512 + d], cw[d * 4 + t], acc);
  }
  u[idx] = acc / (1.f + __expf(-acc));
}

// ---------------- K4a: dbc = u @ x_proj_w^T  (M=16384, N=40, K=256)
__global__ __launch_bounds__(256) void xproj_kernel(
    const float* __restrict__ u, const float* __restrict__ W,
    float* __restrict__ dbc) {
  __shared__ float Wsh[40 * 257];
  __shared__ float As[64][33];
  int m0 = blockIdx.x * 64;
  int tid = threadIdx.x;
  for (int e = tid; e < 40 * 256; e += 256) {
    int r = e >> 8, c = e & 255;
    Wsh[r * 257 + c] = W[e];
  }
  int mi = tid >> 2, nq = tid & 3;
  float acc[10];
#pragma unroll
  for (int j = 0; j < 10; ++j) acc[j] = 0.f;
  for (int k0 = 0; k0 < 256; k0 += 32) {
    __syncthreads();
    for (int e = tid; e < 512; e += 256) {
      int r = e >> 3, c4 = (e & 7) << 2;
      float4 v = *(const float4*)(u + (size_t)(m0 + r) * 256 + k0 + c4);
      As[r][c4] = v.x; As[r][c4 + 1] = v.y;
      As[r][c4 + 2] = v.z; As[r][c4 + 3] = v.w;
    }
    __syncthreads();
    for (int kk = 0; kk < 32; ++kk) {
      float a = As[mi][kk];
#pragma unroll
      for (int j = 0; j < 10; ++j)
        acc[j] = fmaf(a, Wsh[(nq + 4 * j) * 257 + k0 + kk], acc[j]);
    }
  }
  size_t base = (size_t)(m0 + mi) * 40 + nq;
#pragma unroll
  for (int j = 0; j < 10; ++j) dbc[base + 4 * j] = acc[j];
}

// ---------------- K4b: delta = softplus(dt @ dt_proj_w^T + b)
__global__ __launch_bounds__(256) void delta_kernel(
    const float* __restrict__ dbc, const float* __restrict__ Wdt,
    const float* __restrict__ bdt, float* __restrict__ delta) {
  int idx = blockIdx.x * 256 + threadIdx.x;  // over B*L*256
  int d = idx & 255;
  int m = idx >> 8;
  float acc = bdt[d];
#pragma unroll
  for (int j = 0; j < 8; ++j)
    acc = fmaf(dbc[(size_t)m * 40 + j], Wdt[d * 8 + j], acc);
  delta[idx] = (acc > 20.f) ? acc : log1pf(__expf(acc));
}

// ---------------- K5: selective scan. block = (b, 16-d slice); lanes = 4d x 16n
// y may alias delta: chunk rows are fully read into LDS before being overwritten,
// and blocks own disjoint d-columns.
__global__ __launch_bounds__(256) void scan_kernel(
    const float* __restrict__ delta, const float* __restrict__ u,
    const float* __restrict__ dbc, const float* __restrict__ A_log,
    const float* __restrict__ Dp, float* __restrict__ y) {
  int b = blockIdx.x >> 4;
  int dblk = blockIdx.x & 15;
  int tid = threadIdx.x;
  int dd = tid >> 4, n = tid & 15;
  int d = dblk * 16 + dd;
  float Ac = -__expf(A_log[d * 16 + n]);
  float Dv = Dp[d];
  __shared__ float dl[64][16], ul[64][16], Bl[64][16], Cl[64][16];
  float h = 0.f;
  size_t base_du = (size_t)b * L_SEQ * 256 + dblk * 16;
  size_t base_bc = (size_t)b * L_SEQ * 40;
  for (int l0 = 0; l0 < L_SEQ; l0 += 64) {
    __syncthreads();
    for (int e = tid; e < 1024; e += 256) {
      int li = e >> 4, q = e & 15;
      size_t row = (size_t)(l0 + li);
      dl[li][q] = delta[base_du + row * 256 + q];
      ul[li][q] = u[base_du + row * 256 + q];
      Bl[li][q] = dbc[base_bc + row * 40 + 8 + q];
      Cl[li][q] = dbc[base_bc + row * 40 + 24 + q];
    }
    __syncthreads();
#pragma unroll 4
    for (int li = 0; li < 64; ++li) {
      float dv = dl[li][dd];
      float uv = ul[li][dd];
      float dA = __expf(dv * Ac);
      h = fmaf(dA, h, dv * Bl[li][n] * uv);
      float p = h * Cl[li][n];
      p += __shfl_xor(p, 1, 64);
      p += __shfl_xor(p, 2, 64);
      p += __shfl_xor(p, 4, 64);
      p += __shfl_xor(p, 8, 64);
      if (n == 0)
        y[base_du + (size_t)(l0 + li) * 256 + dd] = fmaf(uv, Dv, p);
    }
  }
}

// ---------------- K6a: y *= silu(z)
__global__ __launch_bounds__(256) void gate_kernel(
    const float* __restrict__ xz, float* __restrict__ y) {
  int idx = blockIdx.x * 256 + threadIdx.x;  // over B*L*256
  int d = idx & 255;
  int m = idx >> 8;
  float z = xz[(size_t)m * 512 + 256 + d];
  float s = z / (1.f + __expf(-z));
  y[idx] *= s;
}

// ---------------- K6c: LayerNorm(ch) + silu + 1x1 conv -> out (B,64,H2,W2)
__global__ __launch_bounds__(128) void ln_out_kernel(
    const float* __restrict__ s2, const float* __restrict__ gamma,
    const float* __restrict__ beta, const float* __restrict__ Wo,
    const float* __restrict__ bo, float* __restrict__ out) {
  __shared__ float row[128];
  __shared__ float redS[2], redQ[2];
  int m = blockIdx.x;
  int c = threadIdx.x;
  float v = s2[(size_t)m * 128 + c];
  float s = v, q = v * v;
#pragma unroll
  for (int off = 1; off <= 32; off <<= 1) {
    s += __shfl_xor(s, off, 64);
    q += __shfl_xor(q, off, 64);
  }
  if ((c & 63) == 0) { redS[c >> 6] = s; redQ[c >> 6] = q; }
  __syncthreads();
  float S = redS[0] + redS[1];
  float Q = redQ[0] + redQ[1];
  float mu = S * (1.f / 128.f);
  float var = Q * (1.f / 128.f) - mu * mu;
  float inv = rsqrtf(var + 1e-5f);
  float xn = (v - mu) * inv * gamma[c] + beta[c];
  row[c] = xn / (1.f + __expf(-xn));
  __syncthreads();
  if (c < 64) {
    float acc = bo[c];
#pragma unroll 16
    for (int k = 0; k < 128; ++k)
      acc = fmaf(row[k], Wo[c * 128 + k], acc);
    int b = m >> 12, l = m & 4095;
    out[((size_t)b * 64 + c) * 4096 + l] = acc;
  }
}

extern "C" void kernel_launch(void* const* d_in, const int* in_sizes, int n_in,
                              void* d_out, int out_size, void* d_ws, size_t ws_size,
                              hipStream_t stream) {
  (void)in_sizes; (void)n_in; (void)out_size; (void)ws_size;
  const float* x         = (const float*)d_in[0];
  const float* skip      = (const float*)d_in[1];
  const float* up_w      = (const float*)d_in[2];
  const float* up_b      = (const float*)d_in[3];
  const float* in_proj_w = (const float*)d_in[4];
  const float* conv1d_w  = (const float*)d_in[5];
  const float* conv1d_b  = (const float*)d_in[6];
  const float* x_proj_w  = (const float*)d_in[7];
  const float* dt_proj_w = (const float*)d_in[8];
  const float* dt_proj_b = (const float*)d_in[9];
  const float* A_log     = (const float*)d_in[10];
  const float* Dp        = (const float*)d_in[11];
  const float* out_proj_w= (const float*)d_in[12];
  const float* ln_gamma  = (const float*)d_in[13];
  const float* ln_beta   = (const float*)d_in[14];
  const float* convout_w = (const float*)d_in[15];
  const float* convout_b = (const float*)d_in[16];
  float* out = (float*)d_out;
  float* ws  = (float*)d_ws;

  // workspace layout (floats)
  float* seq   = ws;                  // 2,097,152  (also reused as s2 after out_proj)
  float* xz    = ws + 2097152;        // 8,388,608
  float* u     = ws + 10485760;       // 4,194,304
  float* dbc   = ws + 14680064;       //   655,360
  float* delta = ws + 15335424;       // 4,194,304  (aliased as scan output y)
  float* y     = delta;

  upcat_kernel<<<256, 256, 0, stream>>>(x, skip, up_w, up_b, seq);
  gemm_bt<<<dim3(16384 / 64, 512 / 64), 256, 0, stream>>>(seq, in_proj_w, xz,
                                                          16384, 512, 128);
  conv_silu_kernel<<<16384, 256, 0, stream>>>(xz, conv1d_w, conv1d_b, u);
  xproj_kernel<<<16384 / 64, 256, 0, stream>>>(u, x_proj_w, dbc);
  delta_kernel<<<16384, 256, 0, stream>>>(dbc, dt_proj_w, dt_proj_b, delta);
  scan_kernel<<<64, 256, 0, stream>>>(delta, u, dbc, A_log, Dp, y);
  gate_kernel<<<16384, 256, 0, stream>>>(xz, y);
  gemm_bt<<<dim3(16384 / 64, 128 / 64), 256, 0, stream>>>(y, out_proj_w, seq,
                                                          16384, 128, 256);
  ln_out_kernel<<<16384, 128, 0, stream>>>(seq, ln_gamma, ln_beta, convout_w,
                                           convout_b, out);
}

// Round 2
// 724.692 us; speedup vs baseline: 2.0694x; 2.0694x over previous
//
#include <hip/hip_runtime.h>

#define L_SEQ 4096
#define DM 128
#define DIN 256
#define NC 32        // scan chunks
#define CHUNK 128    // L_SEQ / NC

// ---------------- K1: ConvTranspose2d(2x2,s2) + bias + concat -> seq (B,L,128)
__global__ __launch_bounds__(256) void upcat_kernel(
    const float* __restrict__ x, const float* __restrict__ skip,
    const float* __restrict__ up_w, const float* __restrict__ up_b,
    float* __restrict__ seq) {
  int b = blockIdx.x >> 6, hh = blockIdx.x & 63;
  int h = hh >> 1, i = hh & 1;
  int tid = threadIdx.x;
  __shared__ float xs[128 * 32];     // x[b][c][h][:]
  __shared__ float wsh[128 * 128];   // w[c][o*2+j] for this i
  for (int e = tid; e < 128 * 32; e += 256) {
    int c = e >> 5, w = e & 31;
    xs[e] = x[(((size_t)b * 128 + c) * 32 + h) * 32 + w];
  }
  for (int e = tid; e < 128 * 128; e += 256) {
    int c = e >> 7, oj = e & 127;
    int o = oj >> 1, j = oj & 1;
    wsh[e] = up_w[c * 256 + o * 4 + i * 2 + j];
  }
  __syncthreads();
  int o = tid & 63, wq = tid >> 6;
  float bias = up_b[o];
  size_t mrow_base = (size_t)b * L_SEQ + (size_t)hh * 64;
  for (int s = 0; s < 16; ++s) {
    int ww = wq * 16 + s;
    int w = ww >> 1, j = ww & 1;
    float acc = bias;
#pragma unroll 8
    for (int c = 0; c < 128; ++c)
      acc = fmaf(xs[c * 32 + w], wsh[c * 128 + o * 2 + j], acc);
    seq[(mrow_base + ww) * DM + o] = acc;
  }
  // skip half: channels 64..127
  for (int e = tid; e < 4096; e += 256) {
    int c = e & 63, ww = e >> 6;
    seq[(mrow_base + ww) * DM + 64 + c] =
        skip[((size_t)b * 64 + c) * (size_t)L_SEQ + hh * 64 + ww];
  }
}

// ---------------- generic fp32 GEMM: C[M][N] = A[M][K] @ W[N][K]^T
__global__ __launch_bounds__(256) void gemm_bt(
    const float* __restrict__ A, const float* __restrict__ W,
    float* __restrict__ C, int M, int N, int K) {
  __shared__ float As[32][68];  // [k][m], pad 68
  __shared__ float Ws[32][68];  // [k][n]
  int m0 = blockIdx.x * 64, n0 = blockIdx.y * 64;
  int tid = threadIdx.x;
  int tx = tid & 15, ty = tid >> 4;
  float acc[4][4];
#pragma unroll
  for (int a = 0; a < 4; ++a)
#pragma unroll
    for (int bb = 0; bb < 4; ++bb) acc[a][bb] = 0.f;

  for (int k0 = 0; k0 < K; k0 += 32) {
    __syncthreads();
    for (int e = tid; e < 512; e += 256) {
      int r = e >> 3;
      int c4 = (e & 7) << 2;
      float4 va = *(const float4*)(A + (size_t)(m0 + r) * K + k0 + c4);
      As[c4 + 0][r] = va.x; As[c4 + 1][r] = va.y;
      As[c4 + 2][r] = va.z; As[c4 + 3][r] = va.w;
      float4 vw = *(const float4*)(W + (size_t)(n0 + r) * K + k0 + c4);
      Ws[c4 + 0][r] = vw.x; Ws[c4 + 1][r] = vw.y;
      Ws[c4 + 2][r] = vw.z; Ws[c4 + 3][r] = vw.w;
    }
    __syncthreads();
#pragma unroll
    for (int kk = 0; kk < 32; ++kk) {
      float4 av = *(const float4*)(&As[kk][ty * 4]);
      float4 wv = *(const float4*)(&Ws[kk][tx * 4]);
      float av_[4] = {av.x, av.y, av.z, av.w};
      float wv_[4] = {wv.x, wv.y, wv.z, wv.w};
#pragma unroll
      for (int a = 0; a < 4; ++a)
#pragma unroll
        for (int bb = 0; bb < 4; ++bb)
          acc[a][bb] = fmaf(av_[a], wv_[bb], acc[a][bb]);
    }
  }
#pragma unroll
  for (int a = 0; a < 4; ++a)
#pragma unroll
    for (int bb = 0; bb < 4; ++bb)
      C[(size_t)(m0 + ty * 4 + a) * N + n0 + tx * 4 + bb] = acc[a][bb];
}

// ---------------- K3: depthwise causal conv1d + bias + silu -> u (B,L,256)
__global__ __launch_bounds__(256) void conv_silu_kernel(
    const float* __restrict__ xz, const float* __restrict__ cw,
    const float* __restrict__ cb, float* __restrict__ u) {
  int idx = blockIdx.x * 256 + threadIdx.x;   // over B*L*256
  int d = idx & 255;
  int m = idx >> 8;
  int l = m & (L_SEQ - 1);
  float acc = cb[d];
#pragma unroll
  for (int t = 0; t < 4; ++t) {
    int ls = l - 3 + t;
    if (ls >= 0)
      acc = fmaf(xz[(size_t)(m - 3 + t) * 512 + d], cw[d * 4 + t], acc);
  }
  u[idx] = acc / (1.f + __expf(-acc));
}

// ---------------- K4a: dbc = u @ x_proj_w^T  (M=16384, N=40, K=256)
__global__ __launch_bounds__(256) void xproj_kernel(
    const float* __restrict__ u, const float* __restrict__ W,
    float* __restrict__ dbc) {
  __shared__ float Wsh[40 * 257];
  __shared__ float As[64][33];
  int m0 = blockIdx.x * 64;
  int tid = threadIdx.x;
  for (int e = tid; e < 40 * 256; e += 256) {
    int r = e >> 8, c = e & 255;
    Wsh[r * 257 + c] = W[e];
  }
  int mi = tid >> 2, nq = tid & 3;
  float acc[10];
#pragma unroll
  for (int j = 0; j < 10; ++j) acc[j] = 0.f;
  for (int k0 = 0; k0 < 256; k0 += 32) {
    __syncthreads();
    for (int e = tid; e < 512; e += 256) {
      int r = e >> 3, c4 = (e & 7) << 2;
      float4 v = *(const float4*)(u + (size_t)(m0 + r) * 256 + k0 + c4);
      As[r][c4] = v.x; As[r][c4 + 1] = v.y;
      As[r][c4 + 2] = v.z; As[r][c4 + 3] = v.w;
    }
    __syncthreads();
    for (int kk = 0; kk < 32; ++kk) {
      float a = As[mi][kk];
#pragma unroll
      for (int j = 0; j < 10; ++j)
        acc[j] = fmaf(a, Wsh[(nq + 4 * j) * 257 + k0 + kk], acc[j]);
    }
  }
  size_t base = (size_t)(m0 + mi) * 40 + nq;
#pragma unroll
  for (int j = 0; j < 10; ++j) dbc[base + 4 * j] = acc[j];
}

// ---------------- K4b: delta = softplus(dt @ dt_proj_w^T + b)
__global__ __launch_bounds__(256) void delta_kernel(
    const float* __restrict__ dbc, const float* __restrict__ Wdt,
    const float* __restrict__ bdt, float* __restrict__ delta) {
  int idx = blockIdx.x * 256 + threadIdx.x;  // over B*L*256
  int d = idx & 255;
  int m = idx >> 8;
  float acc = bdt[d];
#pragma unroll
  for (int j = 0; j < 8; ++j)
    acc = fmaf(dbc[(size_t)m * 40 + j], Wdt[d * 8 + j], acc);
  delta[idx] = (acc > 20.f) ? acc : log1pf(__expf(acc));
}

// ---------------- K5: chunked parallel selective scan ----------------
// chains: (b, d, n) = 4*256*16 = 16384; L split into NC chunks of CHUNK.
// pass1: per chunk, from h=0: carryA = prod(dA), carryH = local h.
// pass2: serial over chunks per chain; rewrites carryH[c] := h_in for chunk c.
// pass3: re-run chunk from h_in, emit y = (sum_n h*C + u*D) * silu(z).

__global__ __launch_bounds__(256) void scan_pass1(
    const float* __restrict__ delta, const float* __restrict__ u,
    const float* __restrict__ dbc, const float* __restrict__ A_log,
    float* __restrict__ carryA, float* __restrict__ carryH) {
  int bid = blockIdx.x;            // b*(NC*16) + c*16 + dblk
  int b = bid >> 9;                // NC*16 = 512
  int rem = bid & 511;
  int c = rem >> 4, dblk = rem & 15;
  int tid = threadIdx.x;
  int dd = tid >> 4, n = tid & 15;
  int d = dblk * 16 + dd;
  float Ac = -__expf(A_log[d * 16 + n]);
  __shared__ float dl[CHUNK][16], ul[CHUNK][16], Bl[CHUNK][16];
  size_t base_du = ((size_t)b * L_SEQ + (size_t)c * CHUNK) * 256 + dblk * 16;
  size_t base_bc = ((size_t)b * L_SEQ + (size_t)c * CHUNK) * 40;
  for (int e = tid; e < CHUNK * 16; e += 256) {
    int li = e >> 4, q = e & 15;
    dl[li][q] = delta[base_du + (size_t)li * 256 + q];
    ul[li][q] = u[base_du + (size_t)li * 256 + q];
    Bl[li][q] = dbc[base_bc + (size_t)li * 40 + 8 + q];
  }
  __syncthreads();
  float h = 0.f, Ap = 1.f;
#pragma unroll 4
  for (int li = 0; li < CHUNK; ++li) {
    float dv = dl[li][dd];
    float uv = ul[li][dd];
    float dA = __expf(dv * Ac);
    h = fmaf(dA, h, dv * Bl[li][n] * uv);
    Ap *= dA;
  }
  size_t ci = ((size_t)(b * NC + c) * 256 + d) * 16 + n;
  carryA[ci] = Ap;
  carryH[ci] = h;
}

__global__ __launch_bounds__(256) void scan_mid(
    const float* __restrict__ carryA, float* __restrict__ carryH) {
  int gid = blockIdx.x * 256 + threadIdx.x;  // 16384 chains
  int b = gid >> 12;
  int dn = gid & 4095;
  float h = 0.f;
  for (int c = 0; c < NC; ++c) {
    size_t i = ((size_t)(b * NC + c) << 12) + dn;
    float a = carryA[i];
    float hl = carryH[i];
    carryH[i] = h;                 // h entering chunk c
    h = fmaf(a, h, hl);
  }
}

// y aliases delta: each block stages its chunk's delta slice into LDS (barrier)
// before writing y to exactly those elements; no other block reads them.
__global__ __launch_bounds__(256) void scan_pass3(
    const float* __restrict__ delta, const float* __restrict__ u,
    const float* __restrict__ dbc, const float* __restrict__ xz,
    const float* __restrict__ A_log, const float* __restrict__ Dp,
    const float* __restrict__ carryH, float* __restrict__ y) {
  int bid = blockIdx.x;
  int b = bid >> 9;
  int rem = bid & 511;
  int c = rem >> 4, dblk = rem & 15;
  int tid = threadIdx.x;
  int dd = tid >> 4, n = tid & 15;
  int d = dblk * 16 + dd;
  float Ac = -__expf(A_log[d * 16 + n]);
  float Dv = Dp[d];
  __shared__ float dl[CHUNK][16], ul[CHUNK][16], Bl[CHUNK][16], Cl[CHUNK][16],
      zl[CHUNK][16];
  size_t base_du = ((size_t)b * L_SEQ + (size_t)c * CHUNK) * 256 + dblk * 16;
  size_t base_bc = ((size_t)b * L_SEQ + (size_t)c * CHUNK) * 40;
  size_t base_z = ((size_t)b * L_SEQ + (size_t)c * CHUNK) * 512 + 256 + dblk * 16;
  for (int e = tid; e < CHUNK * 16; e += 256) {
    int li = e >> 4, q = e & 15;
    dl[li][q] = delta[base_du + (size_t)li * 256 + q];
    ul[li][q] = u[base_du + (size_t)li * 256 + q];
    Bl[li][q] = dbc[base_bc + (size_t)li * 40 + 8 + q];
    Cl[li][q] = dbc[base_bc + (size_t)li * 40 + 24 + q];
    zl[li][q] = xz[base_z + (size_t)li * 512 + q];
  }
  size_t ci = ((size_t)(b * NC + c) * 256 + d) * 16 + n;
  float h = carryH[ci];
  __syncthreads();
#pragma unroll 4
  for (int li = 0; li < CHUNK; ++li) {
    float dv = dl[li][dd];
    float uv = ul[li][dd];
    float dA = __expf(dv * Ac);
    h = fmaf(dA, h, dv * Bl[li][n] * uv);
    float p = h * Cl[li][n];
    p += __shfl_xor(p, 1, 64);
    p += __shfl_xor(p, 2, 64);
    p += __shfl_xor(p, 4, 64);
    p += __shfl_xor(p, 8, 64);
    if (n == 0) {
      float z = zl[li][dd];
      float s = z / (1.f + __expf(-z));
      y[base_du + (size_t)li * 256 + dd] = (p + uv * Dv) * s;
    }
  }
}

// ---------------- K6c: LayerNorm(ch) + silu + 1x1 conv -> out (B,64,H2,W2)
__global__ __launch_bounds__(128) void ln_out_kernel(
    const float* __restrict__ s2, const float* __restrict__ gamma,
    const float* __restrict__ beta, const float* __restrict__ Wo,
    const float* __restrict__ bo, float* __restrict__ out) {
  __shared__ float row[128];
  __shared__ float redS[2], redQ[2];
  int m = blockIdx.x;
  int c = threadIdx.x;
  float v = s2[(size_t)m * 128 + c];
  float s = v, q = v * v;
#pragma unroll
  for (int off = 1; off <= 32; off <<= 1) {
    s += __shfl_xor(s, off, 64);
    q += __shfl_xor(q, off, 64);
  }
  if ((c & 63) == 0) { redS[c >> 6] = s; redQ[c >> 6] = q; }
  __syncthreads();
  float S = redS[0] + redS[1];
  float Q = redQ[0] + redQ[1];
  float mu = S * (1.f / 128.f);
  float var = Q * (1.f / 128.f) - mu * mu;
  float inv = rsqrtf(var + 1e-5f);
  float xn = (v - mu) * inv * gamma[c] + beta[c];
  row[c] = xn / (1.f + __expf(-xn));
  __syncthreads();
  if (c < 64) {
    float acc = bo[c];
#pragma unroll 16
    for (int k = 0; k < 128; ++k)
      acc = fmaf(row[k], Wo[c * 128 + k], acc);
    int b = m >> 12, l = m & 4095;
    out[((size_t)b * 64 + c) * 4096 + l] = acc;
  }
}

extern "C" void kernel_launch(void* const* d_in, const int* in_sizes, int n_in,
                              void* d_out, int out_size, void* d_ws, size_t ws_size,
                              hipStream_t stream) {
  (void)in_sizes; (void)n_in; (void)out_size; (void)ws_size;
  const float* x         = (const float*)d_in[0];
  const float* skip      = (const float*)d_in[1];
  const float* up_w      = (const float*)d_in[2];
  const float* up_b      = (const float*)d_in[3];
  const float* in_proj_w = (const float*)d_in[4];
  const float* conv1d_w  = (const float*)d_in[5];
  const float* conv1d_b  = (const float*)d_in[6];
  const float* x_proj_w  = (const float*)d_in[7];
  const float* dt_proj_w = (const float*)d_in[8];
  const float* dt_proj_b = (const float*)d_in[9];
  const float* A_log     = (const float*)d_in[10];
  const float* Dp        = (const float*)d_in[11];
  const float* out_proj_w= (const float*)d_in[12];
  const float* ln_gamma  = (const float*)d_in[13];
  const float* ln_beta   = (const float*)d_in[14];
  const float* convout_w = (const float*)d_in[15];
  const float* convout_b = (const float*)d_in[16];
  float* out = (float*)d_out;
  float* ws  = (float*)d_ws;

  // workspace layout (floats)
  float* seq    = ws;                  // 2,097,152  (reused as s2 after out_proj)
  float* xz     = ws + 2097152;        // 8,388,608
  float* u      = ws + 10485760;       // 4,194,304
  float* dbc    = ws + 14680064;       //   655,360
  float* delta  = ws + 15335424;       // 4,194,304  (aliased as scan output y)
  float* carryA = ws + 19529728;       // 2,097,152
  float* carryH = ws + 21626880;       // 2,097,152
  float* y      = delta;

  upcat_kernel<<<256, 256, 0, stream>>>(x, skip, up_w, up_b, seq);
  gemm_bt<<<dim3(16384 / 64, 512 / 64), 256, 0, stream>>>(seq, in_proj_w, xz,
                                                          16384, 512, 128);
  conv_silu_kernel<<<16384, 256, 0, stream>>>(xz, conv1d_w, conv1d_b, u);
  xproj_kernel<<<16384 / 64, 256, 0, stream>>>(u, x_proj_w, dbc);
  delta_kernel<<<16384, 256, 0, stream>>>(dbc, dt_proj_w, dt_proj_b, delta);
  scan_pass1<<<4 * NC * 16, 256, 0, stream>>>(delta, u, dbc, A_log, carryA, carryH);
  scan_mid<<<64, 256, 0, stream>>>(carryA, carryH);
  scan_pass3<<<4 * NC * 16, 256, 0, stream>>>(delta, u, dbc, xz, A_log, Dp,
                                              carryH, y);
  gemm_bt<<<dim3(16384 / 64, 128 / 64), 256, 0, stream>>>(y, out_proj_w, seq,
                                                          16384, 128, 256);
  ln_out_kernel<<<16384, 128, 0, stream>>>(seq, ln_gamma, ln_beta, convout_w,
                                           convout_b, out);
}

// Round 3
// 391.475 us; speedup vs baseline: 3.8309x; 1.8512x over previous
//
#include <hip/hip_runtime.h>

#define L_SEQ 4096
#define DM 128
#define DIN 256
#define NC 32        // scan chunks
#define CHUNK 128    // L_SEQ / NC

// ---------------- K1: ConvTranspose2d(2x2,s2) + bias + concat -> seq (B,L,128)
__global__ __launch_bounds__(256) void upcat_kernel(
    const float* __restrict__ x, const float* __restrict__ skip,
    const float* __restrict__ up_w, const float* __restrict__ up_b,
    float* __restrict__ seq) {
  int b = blockIdx.x >> 6, hh = blockIdx.x & 63;
  int h = hh >> 1, i = hh & 1;
  int tid = threadIdx.x;
  __shared__ float xs[128 * 32];     // x[b][c][h][:]
  __shared__ float wsh[128 * 128];   // w[c][o*2+j] for this i
  for (int e = tid; e < 128 * 32; e += 256) {
    int c = e >> 5, w = e & 31;
    xs[e] = x[(((size_t)b * 128 + c) * 32 + h) * 32 + w];
  }
  for (int e = tid; e < 128 * 128; e += 256) {
    int c = e >> 7, oj = e & 127;
    int o = oj >> 1, j = oj & 1;
    wsh[e] = up_w[c * 256 + o * 4 + i * 2 + j];
  }
  __syncthreads();
  int o = tid & 63, wq = tid >> 6;
  float bias = up_b[o];
  size_t mrow_base = (size_t)b * L_SEQ + (size_t)hh * 64;
  for (int s = 0; s < 16; ++s) {
    int ww = wq * 16 + s;
    int w = ww >> 1, j = ww & 1;
    float acc = bias;
#pragma unroll 8
    for (int c = 0; c < 128; ++c)
      acc = fmaf(xs[c * 32 + w], wsh[c * 128 + o * 2 + j], acc);
    seq[(mrow_base + ww) * DM + o] = acc;
  }
  // skip half: channels 64..127
  for (int e = tid; e < 4096; e += 256) {
    int c = e & 63, ww = e >> 6;
    seq[(mrow_base + ww) * DM + 64 + c] =
        skip[((size_t)b * 64 + c) * (size_t)L_SEQ + hh * 64 + ww];
  }
}

// ---------------- generic fp32 GEMM: C[M][N] = A[M][K] @ W[N][K]^T
__global__ __launch_bounds__(256) void gemm_bt(
    const float* __restrict__ A, const float* __restrict__ W,
    float* __restrict__ C, int M, int N, int K) {
  __shared__ float As[32][68];  // [k][m], pad 68
  __shared__ float Ws[32][68];  // [k][n]
  int m0 = blockIdx.x * 64, n0 = blockIdx.y * 64;
  int tid = threadIdx.x;
  int tx = tid & 15, ty = tid >> 4;
  float acc[4][4];
#pragma unroll
  for (int a = 0; a < 4; ++a)
#pragma unroll
    for (int bb = 0; bb < 4; ++bb) acc[a][bb] = 0.f;

  for (int k0 = 0; k0 < K; k0 += 32) {
    __syncthreads();
    for (int e = tid; e < 512; e += 256) {
      int r = e >> 3;
      int c4 = (e & 7) << 2;
      float4 va = *(const float4*)(A + (size_t)(m0 + r) * K + k0 + c4);
      As[c4 + 0][r] = va.x; As[c4 + 1][r] = va.y;
      As[c4 + 2][r] = va.z; As[c4 + 3][r] = va.w;
      float4 vw = *(const float4*)(W + (size_t)(n0 + r) * K + k0 + c4);
      Ws[c4 + 0][r] = vw.x; Ws[c4 + 1][r] = vw.y;
      Ws[c4 + 2][r] = vw.z; Ws[c4 + 3][r] = vw.w;
    }
    __syncthreads();
#pragma unroll
    for (int kk = 0; kk < 32; ++kk) {
      float4 av = *(const float4*)(&As[kk][ty * 4]);
      float4 wv = *(const float4*)(&Ws[kk][tx * 4]);
      float av_[4] = {av.x, av.y, av.z, av.w};
      float wv_[4] = {wv.x, wv.y, wv.z, wv.w};
#pragma unroll
      for (int a = 0; a < 4; ++a)
#pragma unroll
        for (int bb = 0; bb < 4; ++bb)
          acc[a][bb] = fmaf(av_[a], wv_[bb], acc[a][bb]);
    }
  }
#pragma unroll
  for (int a = 0; a < 4; ++a)
#pragma unroll
    for (int bb = 0; bb < 4; ++bb)
      C[(size_t)(m0 + ty * 4 + a) * N + n0 + tx * 4 + bb] = acc[a][bb];
}

// ---------------- K3: depthwise causal conv1d + bias + silu -> u (B,L,256)
__global__ __launch_bounds__(256) void conv_silu_kernel(
    const float* __restrict__ xz, const float* __restrict__ cw,
    const float* __restrict__ cb, float* __restrict__ u) {
  int idx = blockIdx.x * 256 + threadIdx.x;   // over B*L*256
  int d = idx & 255;
  int m = idx >> 8;
  int l = m & (L_SEQ - 1);
  float acc = cb[d];
#pragma unroll
  for (int t = 0; t < 4; ++t) {
    int ls = l - 3 + t;
    if (ls >= 0)
      acc = fmaf(xz[(size_t)(m - 3 + t) * 512 + d], cw[d * 4 + t], acc);
  }
  u[idx] = acc / (1.f + __expf(-acc));
}

// ---------------- K4a: dbc = u @ x_proj_w^T  (M=16384, N=40, K=256)
// 32 rows/block; thread = (row, 5-output group). W stays in L1/L2 (41 KB,
// reused chip-wide). 8.7 KB LDS for u-rows -> high occupancy, no spills.
__global__ __launch_bounds__(256) void xproj_kernel(
    const float* __restrict__ u, const float* __restrict__ W,
    float* __restrict__ dbc) {
  __shared__ float us[32][68];   // 32 rows x 64-k chunk, pad 68 (272B rows, 16B aligned)
  int m0 = blockIdx.x * 32;
  int tid = threadIdx.x;
  int row = tid >> 3, ng = tid & 7;
  const float* Wb = W + ng * 5 * 256;
  float acc[5];
#pragma unroll
  for (int j = 0; j < 5; ++j) acc[j] = 0.f;
  for (int k0 = 0; k0 < 256; k0 += 64) {
    __syncthreads();
    for (int e = tid; e < 512; e += 256) {
      int r = e >> 4, q = e & 15;
      float4 v = *(const float4*)(u + (size_t)(m0 + r) * 256 + k0 + q * 4);
      *(float4*)&us[r][q * 4] = v;
    }
    __syncthreads();
#pragma unroll 16
    for (int kk = 0; kk < 64; ++kk) {
      float a = us[row][kk];
#pragma unroll
      for (int j = 0; j < 5; ++j)
        acc[j] = fmaf(a, Wb[j * 256 + k0 + kk], acc[j]);
    }
  }
  size_t base = (size_t)(m0 + row) * 40 + ng * 5;
#pragma unroll
  for (int j = 0; j < 5; ++j) dbc[base + j] = acc[j];
}

// ---------------- K4b: delta = softplus(dt @ dt_proj_w^T + b)
__global__ __launch_bounds__(256) void delta_kernel(
    const float* __restrict__ dbc, const float* __restrict__ Wdt,
    const float* __restrict__ bdt, float* __restrict__ delta) {
  int idx = blockIdx.x * 256 + threadIdx.x;  // over B*L*256
  int d = idx & 255;
  int m = idx >> 8;
  float acc = bdt[d];
#pragma unroll
  for (int j = 0; j < 8; ++j)
    acc = fmaf(dbc[(size_t)m * 40 + j], Wdt[d * 8 + j], acc);
  delta[idx] = (acc > 20.f) ? acc : log1pf(__expf(acc));
}

// ---------------- K5: chunked parallel selective scan ----------------
__global__ __launch_bounds__(256) void scan_pass1(
    const float* __restrict__ delta, const float* __restrict__ u,
    const float* __restrict__ dbc, const float* __restrict__ A_log,
    float* __restrict__ carryA, float* __restrict__ carryH) {
  int bid = blockIdx.x;            // b*(NC*16) + c*16 + dblk
  int b = bid >> 9;                // NC*16 = 512
  int rem = bid & 511;
  int c = rem >> 4, dblk = rem & 15;
  int tid = threadIdx.x;
  int dd = tid >> 4, n = tid & 15;
  int d = dblk * 16 + dd;
  float Ac = -__expf(A_log[d * 16 + n]);
  __shared__ float dl[CHUNK][16], ul[CHUNK][16], Bl[CHUNK][16];
  size_t base_du = ((size_t)b * L_SEQ + (size_t)c * CHUNK) * 256 + dblk * 16;
  size_t base_bc = ((size_t)b * L_SEQ + (size_t)c * CHUNK) * 40;
  for (int e = tid; e < CHUNK * 16; e += 256) {
    int li = e >> 4, q = e & 15;
    dl[li][q] = delta[base_du + (size_t)li * 256 + q];
    ul[li][q] = u[base_du + (size_t)li * 256 + q];
    Bl[li][q] = dbc[base_bc + (size_t)li * 40 + 8 + q];
  }
  __syncthreads();
  float h = 0.f, Ap = 1.f;
#pragma unroll 4
  for (int li = 0; li < CHUNK; ++li) {
    float dv = dl[li][dd];
    float uv = ul[li][dd];
    float dA = __expf(dv * Ac);
    h = fmaf(dA, h, dv * Bl[li][n] * uv);
    Ap *= dA;
  }
  size_t ci = ((size_t)(b * NC + c) * 256 + d) * 16 + n;
  carryA[ci] = Ap;
  carryH[ci] = h;
}

__global__ __launch_bounds__(256) void scan_mid(
    const float* __restrict__ carryA, float* __restrict__ carryH) {
  int gid = blockIdx.x * 256 + threadIdx.x;  // 16384 chains
  int b = gid >> 12;
  int dn = gid & 4095;
  float h = 0.f;
  for (int c = 0; c < NC; ++c) {
    size_t i = ((size_t)(b * NC + c) << 12) + dn;
    float a = carryA[i];
    float hl = carryH[i];
    carryH[i] = h;                 // h entering chunk c
    h = fmaf(a, h, hl);
  }
}

// y aliases delta: each block stages its chunk's delta slice into LDS (barrier)
// before writing y to exactly those elements; no other block reads them.
__global__ __launch_bounds__(256) void scan_pass3(
    const float* __restrict__ delta, const float* __restrict__ u,
    const float* __restrict__ dbc, const float* __restrict__ xz,
    const float* __restrict__ A_log, const float* __restrict__ Dp,
    const float* __restrict__ carryH, float* __restrict__ y) {
  int bid = blockIdx.x;
  int b = bid >> 9;
  int rem = bid & 511;
  int c = rem >> 4, dblk = rem & 15;
  int tid = threadIdx.x;
  int dd = tid >> 4, n = tid & 15;
  int d = dblk * 16 + dd;
  float Ac = -__expf(A_log[d * 16 + n]);
  float Dv = Dp[d];
  __shared__ float dl[CHUNK][16], ul[CHUNK][16], Bl[CHUNK][16], Cl[CHUNK][16],
      zl[CHUNK][16];
  size_t base_du = ((size_t)b * L_SEQ + (size_t)c * CHUNK) * 256 + dblk * 16;
  size_t base_bc = ((size_t)b * L_SEQ + (size_t)c * CHUNK) * 40;
  size_t base_z = ((size_t)b * L_SEQ + (size_t)c * CHUNK) * 512 + 256 + dblk * 16;
  for (int e = tid; e < CHUNK * 16; e += 256) {
    int li = e >> 4, q = e & 15;
    dl[li][q] = delta[base_du + (size_t)li * 256 + q];
    ul[li][q] = u[base_du + (size_t)li * 256 + q];
    Bl[li][q] = dbc[base_bc + (size_t)li * 40 + 8 + q];
    Cl[li][q] = dbc[base_bc + (size_t)li * 40 + 24 + q];
    zl[li][q] = xz[base_z + (size_t)li * 512 + q];
  }
  size_t ci = ((size_t)(b * NC + c) * 256 + d) * 16 + n;
  float h = carryH[ci];
  __syncthreads();
#pragma unroll 4
  for (int li = 0; li < CHUNK; ++li) {
    float dv = dl[li][dd];
    float uv = ul[li][dd];
    float dA = __expf(dv * Ac);
    h = fmaf(dA, h, dv * Bl[li][n] * uv);
    float p = h * Cl[li][n];
    p += __shfl_xor(p, 1, 64);
    p += __shfl_xor(p, 2, 64);
    p += __shfl_xor(p, 4, 64);
    p += __shfl_xor(p, 8, 64);
    if (n == 0) {
      float z = zl[li][dd];
      float s = z / (1.f + __expf(-z));
      y[base_du + (size_t)li * 256 + dd] = (p + uv * Dv) * s;
    }
  }
}

// ---------------- K6c: LayerNorm(ch) + silu + 1x1 conv -> out (B,64,H2,W2)
__global__ __launch_bounds__(128) void ln_out_kernel(
    const float* __restrict__ s2, const float* __restrict__ gamma,
    const float* __restrict__ beta, const float* __restrict__ Wo,
    const float* __restrict__ bo, float* __restrict__ out) {
  __shared__ float row[128];
  __shared__ float redS[2], redQ[2];
  int m = blockIdx.x;
  int c = threadIdx.x;
  float v = s2[(size_t)m * 128 + c];
  float s = v, q = v * v;
#pragma unroll
  for (int off = 1; off <= 32; off <<= 1) {
    s += __shfl_xor(s, off, 64);
    q += __shfl_xor(q, off, 64);
  }
  if ((c & 63) == 0) { redS[c >> 6] = s; redQ[c >> 6] = q; }
  __syncthreads();
  float S = redS[0] + redS[1];
  float Q = redQ[0] + redQ[1];
  float mu = S * (1.f / 128.f);
  float var = Q * (1.f / 128.f) - mu * mu;
  float inv = rsqrtf(var + 1e-5f);
  float xn = (v - mu) * inv * gamma[c] + beta[c];
  row[c] = xn / (1.f + __expf(-xn));
  __syncthreads();
  if (c < 64) {
    float acc = bo[c];
#pragma unroll 16
    for (int k = 0; k < 128; ++k)
      acc = fmaf(row[k], Wo[c * 128 + k], acc);
    int b = m >> 12, l = m & 4095;
    out[((size_t)b * 64 + c) * 4096 + l] = acc;
  }
}

extern "C" void kernel_launch(void* const* d_in, const int* in_sizes, int n_in,
                              void* d_out, int out_size, void* d_ws, size_t ws_size,
                              hipStream_t stream) {
  (void)in_sizes; (void)n_in; (void)out_size; (void)ws_size;
  const float* x         = (const float*)d_in[0];
  const float* skip      = (const float*)d_in[1];
  const float* up_w      = (const float*)d_in[2];
  const float* up_b      = (const float*)d_in[3];
  const float* in_proj_w = (const float*)d_in[4];
  const float* conv1d_w  = (const float*)d_in[5];
  const float* conv1d_b  = (const float*)d_in[6];
  const float* x_proj_w  = (const float*)d_in[7];
  const float* dt_proj_w = (const float*)d_in[8];
  const float* dt_proj_b = (const float*)d_in[9];
  const float* A_log     = (const float*)d_in[10];
  const float* Dp        = (const float*)d_in[11];
  const float* out_proj_w= (const float*)d_in[12];
  const float* ln_gamma  = (const float*)d_in[13];
  const float* ln_beta   = (const float*)d_in[14];
  const float* convout_w = (const float*)d_in[15];
  const float* convout_b = (const float*)d_in[16];
  float* out = (float*)d_out;
  float* ws  = (float*)d_ws;

  // workspace layout (floats)
  float* seq    = ws;                  // 2,097,152  (reused as s2 after out_proj)
  float* xz     = ws + 2097152;        // 8,388,608
  float* u      = ws + 10485760;       // 4,194,304
  float* dbc    = ws + 14680064;       //   655,360
  float* delta  = ws + 15335424;       // 4,194,304  (aliased as scan output y)
  float* carryA = ws + 19529728;       // 2,097,152
  float* carryH = ws + 21626880;       // 2,097,152
  float* y      = delta;

  upcat_kernel<<<256, 256, 0, stream>>>(x, skip, up_w, up_b, seq);
  gemm_bt<<<dim3(16384 / 64, 512 / 64), 256, 0, stream>>>(seq, in_proj_w, xz,
                                                          16384, 512, 128);
  conv_silu_kernel<<<16384, 256, 0, stream>>>(xz, conv1d_w, conv1d_b, u);
  xproj_kernel<<<16384 / 32, 256, 0, stream>>>(u, x_proj_w, dbc);
  delta_kernel<<<16384, 256, 0, stream>>>(dbc, dt_proj_w, dt_proj_b, delta);
  scan_pass1<<<4 * NC * 16, 256, 0, stream>>>(delta, u, dbc, A_log, carryA, carryH);
  scan_mid<<<64, 256, 0, stream>>>(carryA, carryH);
  scan_pass3<<<4 * NC * 16, 256, 0, stream>>>(delta, u, dbc, xz, A_log, Dp,
                                              carryH, y);
  gemm_bt<<<dim3(16384 / 64, 128 / 64), 256, 0, stream>>>(y, out_proj_w, seq,
                                                          16384, 128, 256);
  ln_out_kernel<<<16384, 128, 0, stream>>>(seq, ln_gamma, ln_beta, convout_w,
                                           convout_b, out);
}

// Round 4
// 334.408 us; speedup vs baseline: 4.4846x; 1.1706x over previous
//
#include <hip/hip_runtime.h>

#define L_SEQ 4096
#define DM 128
#define DIN 256
#define NC 128       // scan chunks
#define CHUNK 32     // L_SEQ / NC

// ---------------- K1: ConvTranspose2d(2x2,s2) + bias + concat -> seq (B,L,128)
__global__ __launch_bounds__(256) void upcat_kernel(
    const float* __restrict__ x, const float* __restrict__ skip,
    const float* __restrict__ up_w, const float* __restrict__ up_b,
    float* __restrict__ seq) {
  int b = blockIdx.x >> 6, hh = blockIdx.x & 63;
  int h = hh >> 1, i = hh & 1;
  int tid = threadIdx.x;
  __shared__ float xs[128 * 32];     // x[b][c][h][:]
  __shared__ float wsh[128 * 128];   // w[c][o*2+j] for this i
  for (int e = tid; e < 128 * 32; e += 256) {
    int c = e >> 5, w = e & 31;
    xs[e] = x[(((size_t)b * 128 + c) * 32 + h) * 32 + w];
  }
  for (int e = tid; e < 128 * 128; e += 256) {
    int c = e >> 7, oj = e & 127;
    int o = oj >> 1, j = oj & 1;
    wsh[e] = up_w[c * 256 + o * 4 + i * 2 + j];
  }
  __syncthreads();
  int o = tid & 63, wq = tid >> 6;
  float bias = up_b[o];
  size_t mrow_base = (size_t)b * L_SEQ + (size_t)hh * 64;
  for (int s = 0; s < 16; ++s) {
    int ww = wq * 16 + s;
    int w = ww >> 1, j = ww & 1;
    float acc = bias;
#pragma unroll 8
    for (int c = 0; c < 128; ++c)
      acc = fmaf(xs[c * 32 + w], wsh[c * 128 + o * 2 + j], acc);
    seq[(mrow_base + ww) * DM + o] = acc;
  }
  // skip half: channels 64..127
  for (int e = tid; e < 4096; e += 256) {
    int c = e & 63, ww = e >> 6;
    seq[(mrow_base + ww) * DM + 64 + c] =
        skip[((size_t)b * 64 + c) * (size_t)L_SEQ + hh * 64 + ww];
  }
}

// ---------------- generic fp32 GEMM: C[M][N] = A[M][K] @ W[N][K]^T
__global__ __launch_bounds__(256) void gemm_bt(
    const float* __restrict__ A, const float* __restrict__ W,
    float* __restrict__ C, int M, int N, int K) {
  __shared__ float As[32][68];  // [k][m], pad 68
  __shared__ float Ws[32][68];  // [k][n]
  int m0 = blockIdx.x * 64, n0 = blockIdx.y * 64;
  int tid = threadIdx.x;
  int tx = tid & 15, ty = tid >> 4;
  float acc[4][4];
#pragma unroll
  for (int a = 0; a < 4; ++a)
#pragma unroll
    for (int bb = 0; bb < 4; ++bb) acc[a][bb] = 0.f;

  for (int k0 = 0; k0 < K; k0 += 32) {
    __syncthreads();
    for (int e = tid; e < 512; e += 256) {
      int r = e >> 3;
      int c4 = (e & 7) << 2;
      float4 va = *(const float4*)(A + (size_t)(m0 + r) * K + k0 + c4);
      As[c4 + 0][r] = va.x; As[c4 + 1][r] = va.y;
      As[c4 + 2][r] = va.z; As[c4 + 3][r] = va.w;
      float4 vw = *(const float4*)(W + (size_t)(n0 + r) * K + k0 + c4);
      Ws[c4 + 0][r] = vw.x; Ws[c4 + 1][r] = vw.y;
      Ws[c4 + 2][r] = vw.z; Ws[c4 + 3][r] = vw.w;
    }
    __syncthreads();
#pragma unroll
    for (int kk = 0; kk < 32; ++kk) {
      float4 av = *(const float4*)(&As[kk][ty * 4]);
      float4 wv = *(const float4*)(&Ws[kk][tx * 4]);
      float av_[4] = {av.x, av.y, av.z, av.w};
      float wv_[4] = {wv.x, wv.y, wv.z, wv.w};
#pragma unroll
      for (int a = 0; a < 4; ++a)
#pragma unroll
        for (int bb = 0; bb < 4; ++bb)
          acc[a][bb] = fmaf(av_[a], wv_[bb], acc[a][bb]);
    }
  }
#pragma unroll
  for (int a = 0; a < 4; ++a)
#pragma unroll
    for (int bb = 0; bb < 4; ++bb)
      C[(size_t)(m0 + ty * 4 + a) * N + n0 + tx * 4 + bb] = acc[a][bb];
}

// ---------------- K3: depthwise causal conv1d + bias + silu -> u (B,L,256)
__global__ __launch_bounds__(256) void conv_silu_kernel(
    const float* __restrict__ xz, const float* __restrict__ cw,
    const float* __restrict__ cb, float* __restrict__ u) {
  int idx = blockIdx.x * 256 + threadIdx.x;   // over B*L*256
  int d = idx & 255;
  int m = idx >> 8;
  int l = m & (L_SEQ - 1);
  float acc = cb[d];
#pragma unroll
  for (int t = 0; t < 4; ++t) {
    int ls = l - 3 + t;
    if (ls >= 0)
      acc = fmaf(xz[(size_t)(m - 3 + t) * 512 + d], cw[d * 4 + t], acc);
  }
  u[idx] = acc / (1.f + __expf(-acc));
}

// ---------------- K4a: dbc = u @ x_proj_w^T  (M=16384, N=40, K=256)
__global__ __launch_bounds__(256) void xproj_kernel(
    const float* __restrict__ u, const float* __restrict__ W,
    float* __restrict__ dbc) {
  __shared__ float us[32][68];   // 32 rows x 64-k chunk, pad 68
  int m0 = blockIdx.x * 32;
  int tid = threadIdx.x;
  int row = tid >> 3, ng = tid & 7;
  const float* Wb = W + ng * 5 * 256;
  float acc[5];
#pragma unroll
  for (int j = 0; j < 5; ++j) acc[j] = 0.f;
  for (int k0 = 0; k0 < 256; k0 += 64) {
    __syncthreads();
    for (int e = tid; e < 512; e += 256) {
      int r = e >> 4, q = e & 15;
      float4 v = *(const float4*)(u + (size_t)(m0 + r) * 256 + k0 + q * 4);
      *(float4*)&us[r][q * 4] = v;
    }
    __syncthreads();
#pragma unroll 16
    for (int kk = 0; kk < 64; ++kk) {
      float a = us[row][kk];
#pragma unroll
      for (int j = 0; j < 5; ++j)
        acc[j] = fmaf(a, Wb[j * 256 + k0 + kk], acc[j]);
    }
  }
  size_t base = (size_t)(m0 + row) * 40 + ng * 5;
#pragma unroll
  for (int j = 0; j < 5; ++j) dbc[base + j] = acc[j];
}

// ---------------- K4b: delta = softplus(dt @ dt_proj_w^T + b)
__global__ __launch_bounds__(256) void delta_kernel(
    const float* __restrict__ dbc, const float* __restrict__ Wdt,
    const float* __restrict__ bdt, float* __restrict__ delta) {
  int idx = blockIdx.x * 256 + threadIdx.x;  // over B*L*256
  int d = idx & 255;
  int m = idx >> 8;
  float acc = bdt[d];
#pragma unroll
  for (int j = 0; j < 8; ++j)
    acc = fmaf(dbc[(size_t)m * 40 + j], Wdt[d * 8 + j], acc);
  delta[idx] = (acc > 20.f) ? acc : log1pf(__expf(acc));
}

// ---------------- K5: chunked parallel selective scan ----------------
// thread = (b, chunk, d); its 16 n-states live in registers. No LDS, no
// shuffles: n-reduction is an in-register fma chain; B/C rows are
// block-uniform (scalar loads); delta/u/z reads coalesce across threads.

__global__ __launch_bounds__(256) void scan_pass1(
    const float* __restrict__ delta, const float* __restrict__ u,
    const float* __restrict__ dbc, const float* __restrict__ A_log,
    float* __restrict__ carryA, float* __restrict__ carryH) {
  int bid = blockIdx.x;          // b*NC + c
  int b = bid >> 7;
  int c = bid & (NC - 1);
  int d = threadIdx.x;
  float Ac[16];
  {
    const float4* ar = (const float4*)(A_log + d * 16);
#pragma unroll
    for (int q = 0; q < 4; ++q) {
      float4 v = ar[q];
      Ac[q * 4 + 0] = -__expf(v.x); Ac[q * 4 + 1] = -__expf(v.y);
      Ac[q * 4 + 2] = -__expf(v.z); Ac[q * 4 + 3] = -__expf(v.w);
    }
  }
  float h[16], Ap[16];
#pragma unroll
  for (int n = 0; n < 16; ++n) { h[n] = 0.f; Ap[n] = 1.f; }
  size_t l0 = (size_t)b * L_SEQ + (size_t)c * CHUNK;
  const float* dp = delta + l0 * 256 + d;
  const float* up = u + l0 * 256 + d;
  const float* bc = dbc + l0 * 40 + 8;
  for (int li = 0; li < CHUNK; ++li) {
    float dv = dp[(size_t)li * 256];
    float uv = up[(size_t)li * 256];
    float t = dv * uv;
#pragma unroll
    for (int n = 0; n < 16; ++n) {
      float dA = __expf(dv * Ac[n]);
      h[n] = fmaf(dA, h[n], t * bc[li * 40 + n]);
      Ap[n] *= dA;
    }
  }
  float4* cA = (float4*)(carryA + ((size_t)bid * 256 + d) * 16);
  float4* cH = (float4*)(carryH + ((size_t)bid * 256 + d) * 16);
#pragma unroll
  for (int q = 0; q < 4; ++q) {
    cA[q] = make_float4(Ap[q * 4], Ap[q * 4 + 1], Ap[q * 4 + 2], Ap[q * 4 + 3]);
    cH[q] = make_float4(h[q * 4], h[q * 4 + 1], h[q * 4 + 2], h[q * 4 + 3]);
  }
}

__global__ __launch_bounds__(256) void scan_mid(
    const float* __restrict__ carryA, float* __restrict__ carryH) {
  int gid = blockIdx.x * 256 + threadIdx.x;  // 16384 chains
  int b = gid >> 12;
  int dn = gid & 4095;
  float h = 0.f;
  for (int c = 0; c < NC; ++c) {
    size_t i = ((size_t)(b * NC + c) << 12) + dn;
    float a = carryA[i];
    float hl = carryH[i];
    carryH[i] = h;                 // h entering chunk c
    h = fmaf(a, h, hl);
  }
}

// y aliases delta: each (l,d) element is read and then written by the SAME
// thread within one iteration; no cross-thread sharing of delta in this pass.
__global__ __launch_bounds__(256) void scan_pass3(
    const float* __restrict__ delta, const float* __restrict__ u,
    const float* __restrict__ dbc, const float* __restrict__ xz,
    const float* __restrict__ A_log, const float* __restrict__ Dp,
    const float* __restrict__ carryH, float* __restrict__ y) {
  int bid = blockIdx.x;
  int b = bid >> 7;
  int c = bid & (NC - 1);
  int d = threadIdx.x;
  float Ac[16];
  {
    const float4* ar = (const float4*)(A_log + d * 16);
#pragma unroll
    for (int q = 0; q < 4; ++q) {
      float4 v = ar[q];
      Ac[q * 4 + 0] = -__expf(v.x); Ac[q * 4 + 1] = -__expf(v.y);
      Ac[q * 4 + 2] = -__expf(v.z); Ac[q * 4 + 3] = -__expf(v.w);
    }
  }
  float Dv = Dp[d];
  float h[16];
  {
    const float4* cH = (const float4*)(carryH + ((size_t)bid * 256 + d) * 16);
#pragma unroll
    for (int q = 0; q < 4; ++q) {
      float4 v = cH[q];
      h[q * 4 + 0] = v.x; h[q * 4 + 1] = v.y;
      h[q * 4 + 2] = v.z; h[q * 4 + 3] = v.w;
    }
  }
  size_t l0 = (size_t)b * L_SEQ + (size_t)c * CHUNK;
  const float* dp = delta + l0 * 256 + d;
  const float* up = u + l0 * 256 + d;
  const float* zp = xz + l0 * 512 + 256 + d;
  const float* bc = dbc + l0 * 40 + 8;
  float* yp = y + l0 * 256 + d;
  for (int li = 0; li < CHUNK; ++li) {
    float dv = dp[(size_t)li * 256];
    float uv = up[(size_t)li * 256];
    float zv = zp[(size_t)li * 512];
    float t = dv * uv;
    float p = 0.f;
#pragma unroll
    for (int n = 0; n < 16; ++n) {
      float dA = __expf(dv * Ac[n]);
      h[n] = fmaf(dA, h[n], t * bc[li * 40 + n]);
      p = fmaf(h[n], bc[li * 40 + 16 + n], p);
    }
    float s = zv / (1.f + __expf(-zv));
    yp[(size_t)li * 256] = (p + uv * Dv) * s;
  }
}

// ---------------- K6c: LayerNorm(ch) + silu + 1x1 conv -> out (B,64,H2,W2)
__global__ __launch_bounds__(128) void ln_out_kernel(
    const float* __restrict__ s2, const float* __restrict__ gamma,
    const float* __restrict__ beta, const float* __restrict__ Wo,
    const float* __restrict__ bo, float* __restrict__ out) {
  __shared__ float row[128];
  __shared__ float redS[2], redQ[2];
  int m = blockIdx.x;
  int c = threadIdx.x;
  float v = s2[(size_t)m * 128 + c];
  float s = v, q = v * v;
#pragma unroll
  for (int off = 1; off <= 32; off <<= 1) {
    s += __shfl_xor(s, off, 64);
    q += __shfl_xor(q, off, 64);
  }
  if ((c & 63) == 0) { redS[c >> 6] = s; redQ[c >> 6] = q; }
  __syncthreads();
  float S = redS[0] + redS[1];
  float Q = redQ[0] + redQ[1];
  float mu = S * (1.f / 128.f);
  float var = Q * (1.f / 128.f) - mu * mu;
  float inv = rsqrtf(var + 1e-5f);
  float xn = (v - mu) * inv * gamma[c] + beta[c];
  row[c] = xn / (1.f + __expf(-xn));
  __syncthreads();
  if (c < 64) {
    float acc = bo[c];
#pragma unroll 16
    for (int k = 0; k < 128; ++k)
      acc = fmaf(row[k], Wo[c * 128 + k], acc);
    int b = m >> 12, l = m & 4095;
    out[((size_t)b * 64 + c) * 4096 + l] = acc;
  }
}

extern "C" void kernel_launch(void* const* d_in, const int* in_sizes, int n_in,
                              void* d_out, int out_size, void* d_ws, size_t ws_size,
                              hipStream_t stream) {
  (void)in_sizes; (void)n_in; (void)out_size; (void)ws_size;
  const float* x         = (const float*)d_in[0];
  const float* skip      = (const float*)d_in[1];
  const float* up_w      = (const float*)d_in[2];
  const float* up_b      = (const float*)d_in[3];
  const float* in_proj_w = (const float*)d_in[4];
  const float* conv1d_w  = (const float*)d_in[5];
  const float* conv1d_b  = (const float*)d_in[6];
  const float* x_proj_w  = (const float*)d_in[7];
  const float* dt_proj_w = (const float*)d_in[8];
  const float* dt_proj_b = (const float*)d_in[9];
  const float* A_log     = (const float*)d_in[10];
  const float* Dp        = (const float*)d_in[11];
  const float* out_proj_w= (const float*)d_in[12];
  const float* ln_gamma  = (const float*)d_in[13];
  const float* ln_beta   = (const float*)d_in[14];
  const float* convout_w = (const float*)d_in[15];
  const float* convout_b = (const float*)d_in[16];
  float* out = (float*)d_out;
  float* ws  = (float*)d_ws;

  // workspace layout (floats)
  float* seq    = ws;                  // 2,097,152  (reused as s2 after out_proj)
  float* xz     = ws + 2097152;        // 8,388,608
  float* u      = ws + 10485760;       // 4,194,304
  float* dbc    = ws + 14680064;       //   655,360
  float* delta  = ws + 15335424;       // 4,194,304  (aliased as scan output y)
  float* carryA = ws + 19529728;       // 2,097,152  (= 4*NC*256*16)
  float* carryH = ws + 21626880;       // 2,097,152
  float* y      = delta;

  upcat_kernel<<<256, 256, 0, stream>>>(x, skip, up_w, up_b, seq);
  gemm_bt<<<dim3(16384 / 64, 512 / 64), 256, 0, stream>>>(seq, in_proj_w, xz,
                                                          16384, 512, 128);
  conv_silu_kernel<<<16384, 256, 0, stream>>>(xz, conv1d_w, conv1d_b, u);
  xproj_kernel<<<16384 / 32, 256, 0, stream>>>(u, x_proj_w, dbc);
  delta_kernel<<<16384, 256, 0, stream>>>(dbc, dt_proj_w, dt_proj_b, delta);
  scan_pass1<<<4 * NC, 256, 0, stream>>>(delta, u, dbc, A_log, carryA, carryH);
  scan_mid<<<64, 256, 0, stream>>>(carryA, carryH);
  scan_pass3<<<4 * NC, 256, 0, stream>>>(delta, u, dbc, xz, A_log, Dp,
                                         carryH, y);
  gemm_bt<<<dim3(16384 / 64, 128 / 64), 256, 0, stream>>>(y, out_proj_w, seq,
                                                          16384, 128, 256);
  ln_out_kernel<<<16384, 128, 0, stream>>>(seq, ln_gamma, ln_beta, convout_w,
                                           convout_b, out);
}

// Round 5
// 318.245 us; speedup vs baseline: 4.7124x; 1.0508x over previous
//
#include <hip/hip_runtime.h>

#define L_SEQ 4096
#define DM 128
#define DIN 256
#define NC 128       // scan chunks
#define CHUNK 32     // L_SEQ / NC

// ---------------- K1: ConvTranspose2d(2x2,s2) + bias + concat -> seq (B,L,128)
__global__ __launch_bounds__(256) void upcat_kernel(
    const float* __restrict__ x, const float* __restrict__ skip,
    const float* __restrict__ up_w, const float* __restrict__ up_b,
    float* __restrict__ seq) {
  int b = blockIdx.x >> 6, hh = blockIdx.x & 63;
  int h = hh >> 1, i = hh & 1;
  int tid = threadIdx.x;
  __shared__ float xs[128 * 32];     // x[b][c][h][:]
  __shared__ float wsh[128 * 128];   // w[c][o*2+j] for this i
  for (int e = tid; e < 128 * 32; e += 256) {
    int c = e >> 5, w = e & 31;
    xs[e] = x[(((size_t)b * 128 + c) * 32 + h) * 32 + w];
  }
  for (int e = tid; e < 128 * 128; e += 256) {
    int c = e >> 7, oj = e & 127;
    int o = oj >> 1, j = oj & 1;
    wsh[e] = up_w[c * 256 + o * 4 + i * 2 + j];
  }
  __syncthreads();
  int o = tid & 63, wq = tid >> 6;
  float bias = up_b[o];
  size_t mrow_base = (size_t)b * L_SEQ + (size_t)hh * 64;
  for (int s = 0; s < 16; ++s) {
    int ww = wq * 16 + s;
    int w = ww >> 1, j = ww & 1;
    float acc = bias;
#pragma unroll 8
    for (int c = 0; c < 128; ++c)
      acc = fmaf(xs[c * 32 + w], wsh[c * 128 + o * 2 + j], acc);
    seq[(mrow_base + ww) * DM + o] = acc;
  }
  // skip half: channels 64..127
  for (int e = tid; e < 4096; e += 256) {
    int c = e & 63, ww = e >> 6;
    seq[(mrow_base + ww) * DM + 64 + c] =
        skip[((size_t)b * 64 + c) * (size_t)L_SEQ + hh * 64 + ww];
  }
}

// ---------------- generic fp32 GEMM: C[M][N] = A[M][K] @ W[N][K]^T
__global__ __launch_bounds__(256) void gemm_bt(
    const float* __restrict__ A, const float* __restrict__ W,
    float* __restrict__ C, int M, int N, int K) {
  __shared__ float As[32][68];  // [k][m], pad 68
  __shared__ float Ws[32][68];  // [k][n]
  int m0 = blockIdx.x * 64, n0 = blockIdx.y * 64;
  int tid = threadIdx.x;
  int tx = tid & 15, ty = tid >> 4;
  float acc[4][4];
#pragma unroll
  for (int a = 0; a < 4; ++a)
#pragma unroll
    for (int bb = 0; bb < 4; ++bb) acc[a][bb] = 0.f;

  for (int k0 = 0; k0 < K; k0 += 32) {
    __syncthreads();
    for (int e = tid; e < 512; e += 256) {
      int r = e >> 3;
      int c4 = (e & 7) << 2;
      float4 va = *(const float4*)(A + (size_t)(m0 + r) * K + k0 + c4);
      As[c4 + 0][r] = va.x; As[c4 + 1][r] = va.y;
      As[c4 + 2][r] = va.z; As[c4 + 3][r] = va.w;
      float4 vw = *(const float4*)(W + (size_t)(n0 + r) * K + k0 + c4);
      Ws[c4 + 0][r] = vw.x; Ws[c4 + 1][r] = vw.y;
      Ws[c4 + 2][r] = vw.z; Ws[c4 + 3][r] = vw.w;
    }
    __syncthreads();
#pragma unroll
    for (int kk = 0; kk < 32; ++kk) {
      float4 av = *(const float4*)(&As[kk][ty * 4]);
      float4 wv = *(const float4*)(&Ws[kk][tx * 4]);
      float av_[4] = {av.x, av.y, av.z, av.w};
      float wv_[4] = {wv.x, wv.y, wv.z, wv.w};
#pragma unroll
      for (int a = 0; a < 4; ++a)
#pragma unroll
        for (int bb = 0; bb < 4; ++bb)
          acc[a][bb] = fmaf(av_[a], wv_[bb], acc[a][bb]);
    }
  }
#pragma unroll
  for (int a = 0; a < 4; ++a)
#pragma unroll
    for (int bb = 0; bb < 4; ++bb)
      C[(size_t)(m0 + ty * 4 + a) * N + n0 + tx * 4 + bb] = acc[a][bb];
}

// ---------------- K3: depthwise causal conv1d + bias + silu -> u (B,L,256)
__global__ __launch_bounds__(256) void conv_silu_kernel(
    const float* __restrict__ xz, const float* __restrict__ cw,
    const float* __restrict__ cb, float* __restrict__ u) {
  int idx = blockIdx.x * 256 + threadIdx.x;   // over B*L*256
  int d = idx & 255;
  int m = idx >> 8;
  int l = m & (L_SEQ - 1);
  float acc = cb[d];
#pragma unroll
  for (int t = 0; t < 4; ++t) {
    int ls = l - 3 + t;
    if (ls >= 0)
      acc = fmaf(xz[(size_t)(m - 3 + t) * 512 + d], cw[d * 4 + t], acc);
  }
  u[idx] = acc / (1.f + __expf(-acc));
}

// ---------------- K4a: dbc = u @ x_proj_w^T  (M=16384, N=40, K=256)
// 4 waves/block; wave w -> output rows w*10..w*10+9 (wave-uniform => W reads
// become s_loads feeding FMA scalar operands). Lane owns one of 64 u-rows.
__global__ __launch_bounds__(256) void xproj_kernel(
    const float* __restrict__ u, const float* __restrict__ W,
    float* __restrict__ dbc) {
  __shared__ float us[64][68];   // 64 rows x 64-k chunk, pad 68
  int m0 = blockIdx.x * 64;
  int tid = threadIdx.x;
  int lane = tid & 63;
  int w = __builtin_amdgcn_readfirstlane(tid >> 6);  // wave-uniform 0..3
  const float* Wb = W + w * 10 * 256;
  float acc[10];
#pragma unroll
  for (int j = 0; j < 10; ++j) acc[j] = 0.f;
  for (int k0 = 0; k0 < 256; k0 += 64) {
    __syncthreads();
    for (int e = tid; e < 1024; e += 256) {
      int r = e >> 4, q = e & 15;
      float4 v = *(const float4*)(u + (size_t)(m0 + r) * 256 + k0 + q * 4);
      *(float4*)&us[r][q * 4] = v;
    }
    __syncthreads();
#pragma unroll
    for (int kk = 0; kk < 64; kk += 4) {
      float4 a4 = *(const float4*)&us[lane][kk];
      float a_[4] = {a4.x, a4.y, a4.z, a4.w};
#pragma unroll
      for (int i = 0; i < 4; ++i)
#pragma unroll
        for (int j = 0; j < 10; ++j)
          acc[j] = fmaf(a_[i], Wb[j * 256 + k0 + kk + i], acc[j]);
    }
  }
  size_t base = (size_t)(m0 + lane) * 40 + w * 10;
#pragma unroll
  for (int j = 0; j < 10; ++j) dbc[base + j] = acc[j];
}

// ---------------- K5: chunked parallel selective scan ----------------
// thread = (b, chunk, d); 16 n-states in registers. delta is computed on the
// fly from dbc (dt part is thread-uniform -> scalar loads) -- no delta buffer.

__device__ __forceinline__ float softplus_f(float a) {
  return (a > 20.f) ? a : log1pf(__expf(a));
}

__global__ __launch_bounds__(256) void scan_pass1(
    const float* __restrict__ u, const float* __restrict__ dbc,
    const float* __restrict__ A_log, const float* __restrict__ Wdt,
    const float* __restrict__ bdt, float* __restrict__ carryA,
    float* __restrict__ carryH) {
  int bid = blockIdx.x;          // b*NC + c
  int b = bid >> 7;
  int c = bid & (NC - 1);
  int d = threadIdx.x;
  float Ac[16];
  {
    const float4* ar = (const float4*)(A_log + d * 16);
#pragma unroll
    for (int q = 0; q < 4; ++q) {
      float4 v = ar[q];
      Ac[q * 4 + 0] = -__expf(v.x); Ac[q * 4 + 1] = -__expf(v.y);
      Ac[q * 4 + 2] = -__expf(v.z); Ac[q * 4 + 3] = -__expf(v.w);
    }
  }
  float wdt[8];
  {
    const float4* wr = (const float4*)(Wdt + d * 8);
    float4 v0 = wr[0], v1 = wr[1];
    wdt[0] = v0.x; wdt[1] = v0.y; wdt[2] = v0.z; wdt[3] = v0.w;
    wdt[4] = v1.x; wdt[5] = v1.y; wdt[6] = v1.z; wdt[7] = v1.w;
  }
  float bdt_v = bdt[d];
  float h[16], Ap[16];
#pragma unroll
  for (int n = 0; n < 16; ++n) { h[n] = 0.f; Ap[n] = 1.f; }
  size_t l0 = (size_t)b * L_SEQ + (size_t)c * CHUNK;
  const float* up = u + l0 * 256 + d;
  const float* rp = dbc + l0 * 40;
  for (int li = 0; li < CHUNK; ++li) {
    float acc = bdt_v;
#pragma unroll
    for (int j = 0; j < 8; ++j)
      acc = fmaf(rp[li * 40 + j], wdt[j], acc);
    float dv = softplus_f(acc);
    float uv = up[(size_t)li * 256];
    float t = dv * uv;
#pragma unroll
    for (int n = 0; n < 16; ++n) {
      float dA = __expf(dv * Ac[n]);
      h[n] = fmaf(dA, h[n], t * rp[li * 40 + 8 + n]);
      Ap[n] *= dA;
    }
  }
  float4* cA = (float4*)(carryA + ((size_t)bid * 256 + d) * 16);
  float4* cH = (float4*)(carryH + ((size_t)bid * 256 + d) * 16);
#pragma unroll
  for (int q = 0; q < 4; ++q) {
    cA[q] = make_float4(Ap[q * 4], Ap[q * 4 + 1], Ap[q * 4 + 2], Ap[q * 4 + 3]);
    cH[q] = make_float4(h[q * 4], h[q * 4 + 1], h[q * 4 + 2], h[q * 4 + 3]);
  }
}

__global__ __launch_bounds__(256) void scan_mid(
    const float* __restrict__ carryA, float* __restrict__ carryH) {
  int gid = blockIdx.x * 256 + threadIdx.x;  // 16384 chains
  int b = gid >> 12;
  int dn = gid & 4095;
  float h = 0.f;
  for (int c = 0; c < NC; ++c) {
    size_t i = ((size_t)(b * NC + c) << 12) + dn;
    float a = carryA[i];
    float hl = carryH[i];
    carryH[i] = h;                 // h entering chunk c
    h = fmaf(a, h, hl);
  }
}

__global__ __launch_bounds__(256) void scan_pass3(
    const float* __restrict__ u, const float* __restrict__ dbc,
    const float* __restrict__ xz, const float* __restrict__ A_log,
    const float* __restrict__ Wdt, const float* __restrict__ bdt,
    const float* __restrict__ Dp, const float* __restrict__ carryH,
    float* __restrict__ y) {
  int bid = blockIdx.x;
  int b = bid >> 7;
  int c = bid & (NC - 1);
  int d = threadIdx.x;
  float Ac[16];
  {
    const float4* ar = (const float4*)(A_log + d * 16);
#pragma unroll
    for (int q = 0; q < 4; ++q) {
      float4 v = ar[q];
      Ac[q * 4 + 0] = -__expf(v.x); Ac[q * 4 + 1] = -__expf(v.y);
      Ac[q * 4 + 2] = -__expf(v.z); Ac[q * 4 + 3] = -__expf(v.w);
    }
  }
  float wdt[8];
  {
    const float4* wr = (const float4*)(Wdt + d * 8);
    float4 v0 = wr[0], v1 = wr[1];
    wdt[0] = v0.x; wdt[1] = v0.y; wdt[2] = v0.z; wdt[3] = v0.w;
    wdt[4] = v1.x; wdt[5] = v1.y; wdt[6] = v1.z; wdt[7] = v1.w;
  }
  float bdt_v = bdt[d];
  float Dv = Dp[d];
  float h[16];
  {
    const float4* cH = (const float4*)(carryH + ((size_t)bid * 256 + d) * 16);
#pragma unroll
    for (int q = 0; q < 4; ++q) {
      float4 v = cH[q];
      h[q * 4 + 0] = v.x; h[q * 4 + 1] = v.y;
      h[q * 4 + 2] = v.z; h[q * 4 + 3] = v.w;
    }
  }
  size_t l0 = (size_t)b * L_SEQ + (size_t)c * CHUNK;
  const float* up = u + l0 * 256 + d;
  const float* zp = xz + l0 * 512 + 256 + d;
  const float* rp = dbc + l0 * 40;
  float* yp = y + l0 * 256 + d;
  for (int li = 0; li < CHUNK; ++li) {
    float acc = bdt_v;
#pragma unroll
    for (int j = 0; j < 8; ++j)
      acc = fmaf(rp[li * 40 + j], wdt[j], acc);
    float dv = softplus_f(acc);
    float uv = up[(size_t)li * 256];
    float zv = zp[(size_t)li * 512];
    float t = dv * uv;
    float p = 0.f;
#pragma unroll
    for (int n = 0; n < 16; ++n) {
      float dA = __expf(dv * Ac[n]);
      h[n] = fmaf(dA, h[n], t * rp[li * 40 + 8 + n]);
      p = fmaf(h[n], rp[li * 40 + 24 + n], p);
    }
    float s = zv / (1.f + __expf(-zv));
    yp[(size_t)li * 256] = (p + uv * Dv) * s;
  }
}

// ---------------- K6c: LayerNorm(ch) + silu + 1x1 conv -> out (B,64,H2,W2)
__global__ __launch_bounds__(128) void ln_out_kernel(
    const float* __restrict__ s2, const float* __restrict__ gamma,
    const float* __restrict__ beta, const float* __restrict__ Wo,
    const float* __restrict__ bo, float* __restrict__ out) {
  __shared__ float row[128];
  __shared__ float redS[2], redQ[2];
  int m = blockIdx.x;
  int c = threadIdx.x;
  float v = s2[(size_t)m * 128 + c];
  float s = v, q = v * v;
#pragma unroll
  for (int off = 1; off <= 32; off <<= 1) {
    s += __shfl_xor(s, off, 64);
    q += __shfl_xor(q, off, 64);
  }
  if ((c & 63) == 0) { redS[c >> 6] = s; redQ[c >> 6] = q; }
  __syncthreads();
  float S = redS[0] + redS[1];
  float Q = redQ[0] + redQ[1];
  float mu = S * (1.f / 128.f);
  float var = Q * (1.f / 128.f) - mu * mu;
  float inv = rsqrtf(var + 1e-5f);
  float xn = (v - mu) * inv * gamma[c] + beta[c];
  row[c] = xn / (1.f + __expf(-xn));
  __syncthreads();
  if (c < 64) {
    float acc = bo[c];
#pragma unroll 16
    for (int k = 0; k < 128; ++k)
      acc = fmaf(row[k], Wo[c * 128 + k], acc);
    int b = m >> 12, l = m & 4095;
    out[((size_t)b * 64 + c) * 4096 + l] = acc;
  }
}

extern "C" void kernel_launch(void* const* d_in, const int* in_sizes, int n_in,
                              void* d_out, int out_size, void* d_ws, size_t ws_size,
                              hipStream_t stream) {
  (void)in_sizes; (void)n_in; (void)out_size; (void)ws_size;
  const float* x         = (const float*)d_in[0];
  const float* skip      = (const float*)d_in[1];
  const float* up_w      = (const float*)d_in[2];
  const float* up_b      = (const float*)d_in[3];
  const float* in_proj_w = (const float*)d_in[4];
  const float* conv1d_w  = (const float*)d_in[5];
  const float* conv1d_b  = (const float*)d_in[6];
  const float* x_proj_w  = (const float*)d_in[7];
  const float* dt_proj_w = (const float*)d_in[8];
  const float* dt_proj_b = (const float*)d_in[9];
  const float* A_log     = (const float*)d_in[10];
  const float* Dp        = (const float*)d_in[11];
  const float* out_proj_w= (const float*)d_in[12];
  const float* ln_gamma  = (const float*)d_in[13];
  const float* ln_beta   = (const float*)d_in[14];
  const float* convout_w = (const float*)d_in[15];
  const float* convout_b = (const float*)d_in[16];
  float* out = (float*)d_out;
  float* ws  = (float*)d_ws;

  // workspace layout (floats)
  float* seq    = ws;                  // 2,097,152  (reused as s2 after out_proj)
  float* xz     = ws + 2097152;        // 8,388,608
  float* u      = ws + 10485760;       // 4,194,304
  float* dbc    = ws + 14680064;       //   655,360
  float* y      = ws + 15335424;       // 4,194,304
  float* carryA = ws + 19529728;       // 2,097,152  (= 4*NC*256*16)
  float* carryH = ws + 21626880;       // 2,097,152

  upcat_kernel<<<256, 256, 0, stream>>>(x, skip, up_w, up_b, seq);
  gemm_bt<<<dim3(16384 / 64, 512 / 64), 256, 0, stream>>>(seq, in_proj_w, xz,
                                                          16384, 512, 128);
  conv_silu_kernel<<<16384, 256, 0, stream>>>(xz, conv1d_w, conv1d_b, u);
  xproj_kernel<<<16384 / 64, 256, 0, stream>>>(u, x_proj_w, dbc);
  scan_pass1<<<4 * NC, 256, 0, stream>>>(u, dbc, A_log, dt_proj_w, dt_proj_b,
                                         carryA, carryH);
  scan_mid<<<64, 256, 0, stream>>>(carryA, carryH);
  scan_pass3<<<4 * NC, 256, 0, stream>>>(u, dbc, xz, A_log, dt_proj_w,
                                         dt_proj_b, Dp, carryH, y);
  gemm_bt<<<dim3(16384 / 64, 128 / 64), 256, 0, stream>>>(y, out_proj_w, seq,
                                                          16384, 128, 256);
  ln_out_kernel<<<16384, 128, 0, stream>>>(seq, ln_gamma, ln_beta, convout_w,
                                           convout_b, out);
}

// Round 6
// 268.133 us; speedup vs baseline: 5.5931x; 1.1869x over previous
//
#include <hip/hip_runtime.h>

#define L_SEQ 4096
#define DM 128
#define DIN 256
#define NC 128       // scan chunks
#define CHUNK 32     // L_SEQ / NC

// ---------------- K1: ConvTranspose2d(2x2,s2) + bias + concat -> seq (B,L,128)
__global__ __launch_bounds__(256) void upcat_kernel(
    const float* __restrict__ x, const float* __restrict__ skip,
    const float* __restrict__ up_w, const float* __restrict__ up_b,
    float* __restrict__ seq) {
  int b = blockIdx.x >> 6, hh = blockIdx.x & 63;
  int h = hh >> 1, i = hh & 1;
  int tid = threadIdx.x;
  __shared__ float xs[128 * 32];     // x[b][c][h][:]
  __shared__ float wsh[128 * 128];   // w[c][o*2+j] for this i
  for (int e = tid; e < 128 * 32; e += 256) {
    int c = e >> 5, w = e & 31;
    xs[e] = x[(((size_t)b * 128 + c) * 32 + h) * 32 + w];
  }
  for (int e = tid; e < 128 * 128; e += 256) {
    int c = e >> 7, oj = e & 127;
    int o = oj >> 1, j = oj & 1;
    wsh[e] = up_w[c * 256 + o * 4 + i * 2 + j];
  }
  __syncthreads();
  int o = tid & 63, wq = tid >> 6;
  float bias = up_b[o];
  size_t mrow_base = (size_t)b * L_SEQ + (size_t)hh * 64;
  for (int s = 0; s < 16; ++s) {
    int ww = wq * 16 + s;
    int w = ww >> 1, j = ww & 1;
    float acc = bias;
#pragma unroll 8
    for (int c = 0; c < 128; ++c)
      acc = fmaf(xs[c * 32 + w], wsh[c * 128 + o * 2 + j], acc);
    seq[(mrow_base + ww) * DM + o] = acc;
  }
  // skip half: channels 64..127
  for (int e = tid; e < 4096; e += 256) {
    int c = e & 63, ww = e >> 6;
    seq[(mrow_base + ww) * DM + 64 + c] =
        skip[((size_t)b * 64 + c) * (size_t)L_SEQ + hh * 64 + ww];
  }
}

// ---------------- generic fp32 GEMM: C[M][N] = A[M][K] @ W[N][K]^T
__global__ __launch_bounds__(256) void gemm_bt(
    const float* __restrict__ A, const float* __restrict__ W,
    float* __restrict__ C, int M, int N, int K) {
  __shared__ float As[32][68];  // [k][m], pad 68
  __shared__ float Ws[32][68];  // [k][n]
  int m0 = blockIdx.x * 64, n0 = blockIdx.y * 64;
  int tid = threadIdx.x;
  int tx = tid & 15, ty = tid >> 4;
  float acc[4][4];
#pragma unroll
  for (int a = 0; a < 4; ++a)
#pragma unroll
    for (int bb = 0; bb < 4; ++bb) acc[a][bb] = 0.f;

  for (int k0 = 0; k0 < K; k0 += 32) {
    __syncthreads();
    for (int e = tid; e < 512; e += 256) {
      int r = e >> 3;
      int c4 = (e & 7) << 2;
      float4 va = *(const float4*)(A + (size_t)(m0 + r) * K + k0 + c4);
      As[c4 + 0][r] = va.x; As[c4 + 1][r] = va.y;
      As[c4 + 2][r] = va.z; As[c4 + 3][r] = va.w;
      float4 vw = *(const float4*)(W + (size_t)(n0 + r) * K + k0 + c4);
      Ws[c4 + 0][r] = vw.x; Ws[c4 + 1][r] = vw.y;
      Ws[c4 + 2][r] = vw.z; Ws[c4 + 3][r] = vw.w;
    }
    __syncthreads();
#pragma unroll
    for (int kk = 0; kk < 32; ++kk) {
      float4 av = *(const float4*)(&As[kk][ty * 4]);
      float4 wv = *(const float4*)(&Ws[kk][tx * 4]);
      float av_[4] = {av.x, av.y, av.z, av.w};
      float wv_[4] = {wv.x, wv.y, wv.z, wv.w};
#pragma unroll
      for (int a = 0; a < 4; ++a)
#pragma unroll
        for (int bb = 0; bb < 4; ++bb)
          acc[a][bb] = fmaf(av_[a], wv_[bb], acc[a][bb]);
    }
  }
#pragma unroll
  for (int a = 0; a < 4; ++a)
#pragma unroll
    for (int bb = 0; bb < 4; ++bb)
      C[(size_t)(m0 + ty * 4 + a) * N + n0 + tx * 4 + bb] = acc[a][bb];
}

// ---------------- K3: depthwise causal conv1d + bias + silu -> u (B,L,256)
__global__ __launch_bounds__(256) void conv_silu_kernel(
    const float* __restrict__ xz, const float* __restrict__ cw,
    const float* __restrict__ cb, float* __restrict__ u) {
  int idx = blockIdx.x * 256 + threadIdx.x;   // over B*L*256
  int d = idx & 255;
  int m = idx >> 8;
  int l = m & (L_SEQ - 1);
  float acc = cb[d];
#pragma unroll
  for (int t = 0; t < 4; ++t) {
    int ls = l - 3 + t;
    if (ls >= 0)
      acc = fmaf(xz[(size_t)(m - 3 + t) * 512 + d], cw[d * 4 + t], acc);
  }
  u[idx] = acc / (1.f + __expf(-acc));
}

// ---------------- K4a: dbc = u @ x_proj_w^T  (M=16384, N=40, K=256)
// 4 waves/block; wave w -> output rows w*10..w*10+9 (wave-uniform => W reads
// become s_loads feeding FMA scalar operands). Lane owns one of 64 u-rows.
__global__ __launch_bounds__(256) void xproj_kernel(
    const float* __restrict__ u, const float* __restrict__ W,
    float* __restrict__ dbc) {
  __shared__ float us[64][68];   // 64 rows x 64-k chunk, pad 68
  int m0 = blockIdx.x * 64;
  int tid = threadIdx.x;
  int lane = tid & 63;
  int w = __builtin_amdgcn_readfirstlane(tid >> 6);  // wave-uniform 0..3
  const float* Wb = W + w * 10 * 256;
  float acc[10];
#pragma unroll
  for (int j = 0; j < 10; ++j) acc[j] = 0.f;
  for (int k0 = 0; k0 < 256; k0 += 64) {
    __syncthreads();
    for (int e = tid; e < 1024; e += 256) {
      int r = e >> 4, q = e & 15;
      float4 v = *(const float4*)(u + (size_t)(m0 + r) * 256 + k0 + q * 4);
      *(float4*)&us[r][q * 4] = v;
    }
    __syncthreads();
#pragma unroll
    for (int kk = 0; kk < 64; kk += 4) {
      float4 a4 = *(const float4*)&us[lane][kk];
      float a_[4] = {a4.x, a4.y, a4.z, a4.w};
#pragma unroll
      for (int i = 0; i < 4; ++i)
#pragma unroll
        for (int j = 0; j < 10; ++j)
          acc[j] = fmaf(a_[i], Wb[j * 256 + k0 + kk + i], acc[j]);
    }
  }
  size_t base = (size_t)(m0 + lane) * 40 + w * 10;
#pragma unroll
  for (int j = 0; j < 10; ++j) dbc[base + j] = acc[j];
}

// ---------------- K5: chunked parallel selective scan ----------------
// thread = (b, chunk, d); 16 n-states in registers. delta is computed on the
// fly from dbc (dt part is thread-uniform -> scalar loads) -- no delta buffer.

__device__ __forceinline__ float softplus_f(float a) {
  return (a > 20.f) ? a : log1pf(__expf(a));
}

__global__ __launch_bounds__(256) void scan_pass1(
    const float* __restrict__ u, const float* __restrict__ dbc,
    const float* __restrict__ A_log, const float* __restrict__ Wdt,
    const float* __restrict__ bdt, float* __restrict__ carryA,
    float* __restrict__ carryH) {
  int bid = blockIdx.x;          // b*NC + c
  int b = bid >> 7;
  int c = bid & (NC - 1);
  int d = threadIdx.x;
  float Ac[16];
  {
    const float4* ar = (const float4*)(A_log + d * 16);
#pragma unroll
    for (int q = 0; q < 4; ++q) {
      float4 v = ar[q];
      Ac[q * 4 + 0] = -__expf(v.x); Ac[q * 4 + 1] = -__expf(v.y);
      Ac[q * 4 + 2] = -__expf(v.z); Ac[q * 4 + 3] = -__expf(v.w);
    }
  }
  float wdt[8];
  {
    const float4* wr = (const float4*)(Wdt + d * 8);
    float4 v0 = wr[0], v1 = wr[1];
    wdt[0] = v0.x; wdt[1] = v0.y; wdt[2] = v0.z; wdt[3] = v0.w;
    wdt[4] = v1.x; wdt[5] = v1.y; wdt[6] = v1.z; wdt[7] = v1.w;
  }
  float bdt_v = bdt[d];
  float h[16], Ap[16];
#pragma unroll
  for (int n = 0; n < 16; ++n) { h[n] = 0.f; Ap[n] = 1.f; }
  size_t l0 = (size_t)b * L_SEQ + (size_t)c * CHUNK;
  const float* up = u + l0 * 256 + d;
  const float* rp = dbc + l0 * 40;
  for (int li = 0; li < CHUNK; ++li) {
    float acc = bdt_v;
#pragma unroll
    for (int j = 0; j < 8; ++j)
      acc = fmaf(rp[li * 40 + j], wdt[j], acc);
    float dv = softplus_f(acc);
    float uv = up[(size_t)li * 256];
    float t = dv * uv;
#pragma unroll
    for (int n = 0; n < 16; ++n) {
      float dA = __expf(dv * Ac[n]);
      h[n] = fmaf(dA, h[n], t * rp[li * 40 + 8 + n]);
      Ap[n] *= dA;
    }
  }
  float4* cA = (float4*)(carryA + ((size_t)bid * 256 + d) * 16);
  float4* cH = (float4*)(carryH + ((size_t)bid * 256 + d) * 16);
#pragma unroll
  for (int q = 0; q < 4; ++q) {
    cA[q] = make_float4(Ap[q * 4], Ap[q * 4 + 1], Ap[q * 4 + 2], Ap[q * 4 + 3]);
    cH[q] = make_float4(h[q * 4], h[q * 4 + 1], h[q * 4 + 2], h[q * 4 + 3]);
  }
}

__global__ __launch_bounds__(256) void scan_mid(
    const float* __restrict__ carryA, float* __restrict__ carryH) {
  int gid = blockIdx.x * 256 + threadIdx.x;  // 16384 chains
  int b = gid >> 12;
  int dn = gid & 4095;
  float h = 0.f;
  for (int c = 0; c < NC; ++c) {
    size_t i = ((size_t)(b * NC + c) << 12) + dn;
    float a = carryA[i];
    float hl = carryH[i];
    carryH[i] = h;                 // h entering chunk c
    h = fmaf(a, h, hl);
  }
}

__global__ __launch_bounds__(256) void scan_pass3(
    const float* __restrict__ u, const float* __restrict__ dbc,
    const float* __restrict__ xz, const float* __restrict__ A_log,
    const float* __restrict__ Wdt, const float* __restrict__ bdt,
    const float* __restrict__ Dp, const float* __restrict__ carryH,
    float* __restrict__ y) {
  int bid = blockIdx.x;
  int b = bid >> 7;
  int c = bid & (NC - 1);
  int d = threadIdx.x;
  float Ac[16];
  {
    const float4* ar = (const float4*)(A_log + d * 16);
#pragma unroll
    for (int q = 0; q < 4; ++q) {
      float4 v = ar[q];
      Ac[q * 4 + 0] = -__expf(v.x); Ac[q * 4 + 1] = -__expf(v.y);
      Ac[q * 4 + 2] = -__expf(v.z); Ac[q * 4 + 3] = -__expf(v.w);
    }
  }
  float wdt[8];
  {
    const float4* wr = (const float4*)(Wdt + d * 8);
    float4 v0 = wr[0], v1 = wr[1];
    wdt[0] = v0.x; wdt[1] = v0.y; wdt[2] = v0.z; wdt[3] = v0.w;
    wdt[4] = v1.x; wdt[5] = v1.y; wdt[6] = v1.z; wdt[7] = v1.w;
  }
  float bdt_v = bdt[d];
  float Dv = Dp[d];
  float h[16];
  {
    const float4* cH = (const float4*)(carryH + ((size_t)bid * 256 + d) * 16);
#pragma unroll
    for (int q = 0; q < 4; ++q) {
      float4 v = cH[q];
      h[q * 4 + 0] = v.x; h[q * 4 + 1] = v.y;
      h[q * 4 + 2] = v.z; h[q * 4 + 3] = v.w;
    }
  }
  size_t l0 = (size_t)b * L_SEQ + (size_t)c * CHUNK;
  const float* up = u + l0 * 256 + d;
  const float* zp = xz + l0 * 512 + 256 + d;
  const float* rp = dbc + l0 * 40;
  float* yp = y + l0 * 256 + d;
  for (int li = 0; li < CHUNK; ++li) {
    float acc = bdt_v;
#pragma unroll
    for (int j = 0; j < 8; ++j)
      acc = fmaf(rp[li * 40 + j], wdt[j], acc);
    float dv = softplus_f(acc);
    float uv = up[(size_t)li * 256];
    float zv = zp[(size_t)li * 512];
    float t = dv * uv;
    float p = 0.f;
#pragma unroll
    for (int n = 0; n < 16; ++n) {
      float dA = __expf(dv * Ac[n]);
      h[n] = fmaf(dA, h[n], t * rp[li * 40 + 8 + n]);
      p = fmaf(h[n], rp[li * 40 + 24 + n], p);
    }
    float s = zv / (1.f + __expf(-zv));
    yp[(size_t)li * 256] = (p + uv * Dv) * s;
  }
}

// ---------------- K6: LayerNorm(ch) + silu + 1x1 conv -> out (B,64,H2,W2)
// 64 rows/block, grid (256, 2): blockIdx.y picks 32 of 64 output channels so
// each wave's Wo reads are wave-uniform (s_load scalar operands). LN stats
// computed once (4 threads/row + shfl), transform applied in-place in LDS.
__global__ __launch_bounds__(256) void ln_out_kernel(
    const float* __restrict__ s2, const float* __restrict__ gamma,
    const float* __restrict__ beta, const float* __restrict__ Wo,
    const float* __restrict__ bo, float* __restrict__ out) {
  __shared__ float xt[64][129];
  __shared__ float mus[64], invs[64];
  int tid = threadIdx.x;
  int m0 = blockIdx.x * 64;
  // Phase A: coalesced tile load -> LDS
  for (int i = 0; i < 8; ++i) {
    int s = tid + i * 256;          // 2048 float4 slots
    int r = s >> 5, q = s & 31;
    float4 v = *(const float4*)(s2 + (size_t)(m0 + r) * 128 + q * 4);
    xt[r][q * 4 + 0] = v.x; xt[r][q * 4 + 1] = v.y;
    xt[r][q * 4 + 2] = v.z; xt[r][q * 4 + 3] = v.w;
  }
  __syncthreads();
  // Phase B: stats, 4 threads per row
  {
    int r = tid >> 2, kq = (tid & 3) * 32;
    float s = 0.f, q = 0.f;
#pragma unroll 8
    for (int kk = 0; kk < 32; ++kk) {
      float v = xt[r][kq + kk];
      s += v; q = fmaf(v, v, q);
    }
    s += __shfl_xor(s, 1, 64); s += __shfl_xor(s, 2, 64);
    q += __shfl_xor(q, 1, 64); q += __shfl_xor(q, 2, 64);
    if ((tid & 3) == 0) {
      float mu = s * (1.f / 128.f);
      float var = q * (1.f / 128.f) - mu * mu;
      mus[r] = mu;
      invs[r] = rsqrtf(var + 1e-5f);
    }
  }
  __syncthreads();
  // Phase T: LN + silu in-place
  for (int i = 0; i < 32; ++i) {
    int idx = tid + i * 256;        // 8192 elements
    int r = idx >> 7, k = idx & 127;
    float v = xt[r][k];
    float xn = (v - mus[r]) * invs[r] * gamma[k] + beta[k];
    xt[r][k] = xn / (1.f + __expf(-xn));
  }
  __syncthreads();
  // Phase C: GEMM, lane = row, wave-uniform channels
  int lane = tid & 63;
  int w = __builtin_amdgcn_readfirstlane(tid >> 6);
  int cbase = blockIdx.y * 32 + w * 8;
  const float* Wrow = Wo + cbase * 128;
  float acc[8];
#pragma unroll
  for (int j = 0; j < 8; ++j) acc[j] = 0.f;
#pragma unroll 4
  for (int k = 0; k < 128; ++k) {
    float v = xt[lane][k];
#pragma unroll
    for (int j = 0; j < 8; ++j)
      acc[j] = fmaf(v, Wrow[j * 128 + k], acc[j]);
  }
  int m = m0 + lane;
  int b = m >> 12, l = m & 4095;
#pragma unroll
  for (int j = 0; j < 8; ++j)
    out[((size_t)b * 64 + cbase + j) * 4096 + l] = acc[j] + bo[cbase + j];
}

extern "C" void kernel_launch(void* const* d_in, const int* in_sizes, int n_in,
                              void* d_out, int out_size, void* d_ws, size_t ws_size,
                              hipStream_t stream) {
  (void)in_sizes; (void)n_in; (void)out_size; (void)ws_size;
  const float* x         = (const float*)d_in[0];
  const float* skip      = (const float*)d_in[1];
  const float* up_w      = (const float*)d_in[2];
  const float* up_b      = (const float*)d_in[3];
  const float* in_proj_w = (const float*)d_in[4];
  const float* conv1d_w  = (const float*)d_in[5];
  const float* conv1d_b  = (const float*)d_in[6];
  const float* x_proj_w  = (const float*)d_in[7];
  const float* dt_proj_w = (const float*)d_in[8];
  const float* dt_proj_b = (const float*)d_in[9];
  const float* A_log     = (const float*)d_in[10];
  const float* Dp        = (const float*)d_in[11];
  const float* out_proj_w= (const float*)d_in[12];
  const float* ln_gamma  = (const float*)d_in[13];
  const float* ln_beta   = (const float*)d_in[14];
  const float* convout_w = (const float*)d_in[15];
  const float* convout_b = (const float*)d_in[16];
  float* out = (float*)d_out;
  float* ws  = (float*)d_ws;

  // workspace layout (floats)
  float* seq    = ws;                  // 2,097,152  (reused as s2 after out_proj)
  float* xz     = ws + 2097152;        // 8,388,608
  float* u      = ws + 10485760;       // 4,194,304
  float* dbc    = ws + 14680064;       //   655,360
  float* y      = ws + 15335424;       // 4,194,304
  float* carryA = ws + 19529728;       // 2,097,152  (= 4*NC*256*16)
  float* carryH = ws + 21626880;       // 2,097,152

  upcat_kernel<<<256, 256, 0, stream>>>(x, skip, up_w, up_b, seq);
  gemm_bt<<<dim3(16384 / 64, 512 / 64), 256, 0, stream>>>(seq, in_proj_w, xz,
                                                          16384, 512, 128);
  conv_silu_kernel<<<16384, 256, 0, stream>>>(xz, conv1d_w, conv1d_b, u);
  xproj_kernel<<<16384 / 64, 256, 0, stream>>>(u, x_proj_w, dbc);
  scan_pass1<<<4 * NC, 256, 0, stream>>>(u, dbc, A_log, dt_proj_w, dt_proj_b,
                                         carryA, carryH);
  scan_mid<<<64, 256, 0, stream>>>(carryA, carryH);
  scan_pass3<<<4 * NC, 256, 0, stream>>>(u, dbc, xz, A_log, dt_proj_w,
                                         dt_proj_b, Dp, carryH, y);
  gemm_bt<<<dim3(16384 / 64, 128 / 64), 256, 0, stream>>>(y, out_proj_w, seq,
                                                          16384, 128, 256);
  ln_out_kernel<<<dim3(256, 2), 256, 0, stream>>>(seq, ln_gamma, ln_beta,
                                                  convout_w, convout_b, out);
}

// Round 7
// 237.013 us; speedup vs baseline: 6.3275x; 1.1313x over previous
//
#include <hip/hip_runtime.h>

#define L_SEQ 4096
#define DM 128
#define DIN 256
#define NC 128       // scan chunks
#define CHUNK 32     // L_SEQ / NC

// ---------------- K1: ConvTranspose2d(2x2,s2) + bias + concat -> seq (B,L,128)
// block = (b, hh); out[ww][o] = sum_c xs[c][ww>>1] * wsh[ww&1][c][o] + bias.
// Thread owns a 4x4 (ww,o) register tile; wsh reads are ds_read_b128
// (conflict-free), xs reads are wave-broadcast scalars.
__global__ __launch_bounds__(256) void upcat_kernel(
    const float* __restrict__ x, const float* __restrict__ skip,
    const float* __restrict__ up_w, const float* __restrict__ up_b,
    float* __restrict__ seq) {
  int b = blockIdx.x >> 6, hh = blockIdx.x & 63;
  int h = hh >> 1, i = hh & 1;
  int tid = threadIdx.x;
  __shared__ float xs[128][32];      // x[b][c][h][:]
  __shared__ float wsh[2][128][64];  // [j][c][o] for this i
  for (int e = tid; e < 1024; e += 256) {
    int c = e >> 3, q = e & 7;
    *(float4*)&xs[c][q * 4] =
        *(const float4*)(x + (((size_t)b * 128 + c) * 32 + h) * 32 + q * 4);
  }
  for (int e = tid; e < 8192; e += 256) {
    int c = e >> 6, o = e & 63;
    float2 v = *(const float2*)(up_w + c * 256 + o * 4 + i * 2);
    wsh[0][c][o] = v.x;
    wsh[1][c][o] = v.y;
  }
  __syncthreads();
  int tx = tid & 15, ty = tid >> 4;  // o-quad, ww-quad
  float4 bv = *(const float4*)(up_b + tx * 4);
  float acc[4][4];                   // [a -> ww=ty*4+a][o]
#pragma unroll
  for (int a = 0; a < 4; ++a) {
    acc[a][0] = bv.x; acc[a][1] = bv.y; acc[a][2] = bv.z; acc[a][3] = bv.w;
  }
#pragma unroll 4
  for (int c = 0; c < 128; ++c) {
    float x0 = xs[c][ty * 2];        // ww = 4ty+0,1  (w = 2ty)
    float x1 = xs[c][ty * 2 + 1];    // ww = 4ty+2,3  (w = 2ty+1)
    float4 w0 = *(const float4*)&wsh[0][c][tx * 4];
    float4 w1 = *(const float4*)&wsh[1][c][tx * 4];
    acc[0][0] = fmaf(x0, w0.x, acc[0][0]); acc[0][1] = fmaf(x0, w0.y, acc[0][1]);
    acc[0][2] = fmaf(x0, w0.z, acc[0][2]); acc[0][3] = fmaf(x0, w0.w, acc[0][3]);
    acc[1][0] = fmaf(x0, w1.x, acc[1][0]); acc[1][1] = fmaf(x0, w1.y, acc[1][1]);
    acc[1][2] = fmaf(x0, w1.z, acc[1][2]); acc[1][3] = fmaf(x0, w1.w, acc[1][3]);
    acc[2][0] = fmaf(x1, w0.x, acc[2][0]); acc[2][1] = fmaf(x1, w0.y, acc[2][1]);
    acc[2][2] = fmaf(x1, w0.z, acc[2][2]); acc[2][3] = fmaf(x1, w0.w, acc[2][3]);
    acc[3][0] = fmaf(x1, w1.x, acc[3][0]); acc[3][1] = fmaf(x1, w1.y, acc[3][1]);
    acc[3][2] = fmaf(x1, w1.z, acc[3][2]); acc[3][3] = fmaf(x1, w1.w, acc[3][3]);
  }
  size_t mrow_base = (size_t)b * L_SEQ + (size_t)hh * 64;
#pragma unroll
  for (int a = 0; a < 4; ++a) {
    int ww = ty * 4 + a;
    *(float4*)(seq + (mrow_base + ww) * DM + tx * 4) =
        make_float4(acc[a][0], acc[a][1], acc[a][2], acc[a][3]);
  }
  // skip half: channels 64..127
  for (int e = tid; e < 4096; e += 256) {
    int c = e & 63, ww = e >> 6;
    seq[(mrow_base + ww) * DM + 64 + c] =
        skip[((size_t)b * 64 + c) * (size_t)L_SEQ + hh * 64 + ww];
  }
}

// ---------------- generic fp32 GEMM: C[M][N] = A[M][K] @ W[N][K]^T
__global__ __launch_bounds__(256) void gemm_bt(
    const float* __restrict__ A, const float* __restrict__ W,
    float* __restrict__ C, int M, int N, int K) {
  __shared__ float As[32][68];  // [k][m], pad 68
  __shared__ float Ws[32][68];  // [k][n]
  int m0 = blockIdx.x * 64, n0 = blockIdx.y * 64;
  int tid = threadIdx.x;
  int tx = tid & 15, ty = tid >> 4;
  float acc[4][4];
#pragma unroll
  for (int a = 0; a < 4; ++a)
#pragma unroll
    for (int bb = 0; bb < 4; ++bb) acc[a][bb] = 0.f;

  for (int k0 = 0; k0 < K; k0 += 32) {
    __syncthreads();
    for (int e = tid; e < 512; e += 256) {
      int r = e >> 3;
      int c4 = (e & 7) << 2;
      float4 va = *(const float4*)(A + (size_t)(m0 + r) * K + k0 + c4);
      As[c4 + 0][r] = va.x; As[c4 + 1][r] = va.y;
      As[c4 + 2][r] = va.z; As[c4 + 3][r] = va.w;
      float4 vw = *(const float4*)(W + (size_t)(n0 + r) * K + k0 + c4);
      Ws[c4 + 0][r] = vw.x; Ws[c4 + 1][r] = vw.y;
      Ws[c4 + 2][r] = vw.z; Ws[c4 + 3][r] = vw.w;
    }
    __syncthreads();
#pragma unroll
    for (int kk = 0; kk < 32; ++kk) {
      float4 av = *(const float4*)(&As[kk][ty * 4]);
      float4 wv = *(const float4*)(&Ws[kk][tx * 4]);
      float av_[4] = {av.x, av.y, av.z, av.w};
      float wv_[4] = {wv.x, wv.y, wv.z, wv.w};
#pragma unroll
      for (int a = 0; a < 4; ++a)
#pragma unroll
        for (int bb = 0; bb < 4; ++bb)
          acc[a][bb] = fmaf(av_[a], wv_[bb], acc[a][bb]);
    }
  }
#pragma unroll
  for (int a = 0; a < 4; ++a)
#pragma unroll
    for (int bb = 0; bb < 4; ++bb)
      C[(size_t)(m0 + ty * 4 + a) * N + n0 + tx * 4 + bb] = acc[a][bb];
}

// ---------------- K3: depthwise causal conv1d + bias + silu -> u (B,L,256)
__global__ __launch_bounds__(256) void conv_silu_kernel(
    const float* __restrict__ xz, const float* __restrict__ cw,
    const float* __restrict__ cb, float* __restrict__ u) {
  int idx = blockIdx.x * 256 + threadIdx.x;   // over B*L*256
  int d = idx & 255;
  int m = idx >> 8;
  int l = m & (L_SEQ - 1);
  float acc = cb[d];
#pragma unroll
  for (int t = 0; t < 4; ++t) {
    int ls = l - 3 + t;
    if (ls >= 0)
      acc = fmaf(xz[(size_t)(m - 3 + t) * 512 + d], cw[d * 4 + t], acc);
  }
  u[idx] = acc / (1.f + __expf(-acc));
}

// ---------------- K4a: dbc = u @ x_proj_w^T  (M=16384, N=40, K=256)
// 4 waves/block; wave w -> output rows w*10..w*10+9 (wave-uniform => W reads
// become s_loads feeding FMA scalar operands). Lane owns one of 64 u-rows.
__global__ __launch_bounds__(256) void xproj_kernel(
    const float* __restrict__ u, const float* __restrict__ W,
    float* __restrict__ dbc) {
  __shared__ float us[64][68];   // 64 rows x 64-k chunk, pad 68
  int m0 = blockIdx.x * 64;
  int tid = threadIdx.x;
  int lane = tid & 63;
  int w = __builtin_amdgcn_readfirstlane(tid >> 6);  // wave-uniform 0..3
  const float* Wb = W + w * 10 * 256;
  float acc[10];
#pragma unroll
  for (int j = 0; j < 10; ++j) acc[j] = 0.f;
  for (int k0 = 0; k0 < 256; k0 += 64) {
    __syncthreads();
    for (int e = tid; e < 1024; e += 256) {
      int r = e >> 4, q = e & 15;
      float4 v = *(const float4*)(u + (size_t)(m0 + r) * 256 + k0 + q * 4);
      *(float4*)&us[r][q * 4] = v;
    }
    __syncthreads();
#pragma unroll
    for (int kk = 0; kk < 64; kk += 4) {
      float4 a4 = *(const float4*)&us[lane][kk];
      float a_[4] = {a4.x, a4.y, a4.z, a4.w};
#pragma unroll
      for (int i = 0; i < 4; ++i)
#pragma unroll
        for (int j = 0; j < 10; ++j)
          acc[j] = fmaf(a_[i], Wb[j * 256 + k0 + kk + i], acc[j]);
    }
  }
  size_t base = (size_t)(m0 + lane) * 40 + w * 10;
#pragma unroll
  for (int j = 0; j < 10; ++j) dbc[base + j] = acc[j];
}

// ---------------- K5: chunked parallel selective scan ----------------
// thread = (b, chunk, d); 16 n-states in registers. delta is computed on the
// fly from dbc (dt part is thread-uniform -> scalar loads) -- no delta buffer.

__device__ __forceinline__ float softplus_f(float a) {
  return (a > 20.f) ? a : log1pf(__expf(a));
}

__global__ __launch_bounds__(256) void scan_pass1(
    const float* __restrict__ u, const float* __restrict__ dbc,
    const float* __restrict__ A_log, const float* __restrict__ Wdt,
    const float* __restrict__ bdt, float* __restrict__ carryA,
    float* __restrict__ carryH) {
  int bid = blockIdx.x;          // b*NC + c
  int b = bid >> 7;
  int c = bid & (NC - 1);
  int d = threadIdx.x;
  float Ac[16];
  {
    const float4* ar = (const float4*)(A_log + d * 16);
#pragma unroll
    for (int q = 0; q < 4; ++q) {
      float4 v = ar[q];
      Ac[q * 4 + 0] = -__expf(v.x); Ac[q * 4 + 1] = -__expf(v.y);
      Ac[q * 4 + 2] = -__expf(v.z); Ac[q * 4 + 3] = -__expf(v.w);
    }
  }
  float wdt[8];
  {
    const float4* wr = (const float4*)(Wdt + d * 8);
    float4 v0 = wr[0], v1 = wr[1];
    wdt[0] = v0.x; wdt[1] = v0.y; wdt[2] = v0.z; wdt[3] = v0.w;
    wdt[4] = v1.x; wdt[5] = v1.y; wdt[6] = v1.z; wdt[7] = v1.w;
  }
  float bdt_v = bdt[d];
  float h[16], Ap[16];
#pragma unroll
  for (int n = 0; n < 16; ++n) { h[n] = 0.f; Ap[n] = 1.f; }
  size_t l0 = (size_t)b * L_SEQ + (size_t)c * CHUNK;
  const float* up = u + l0 * 256 + d;
  const float* rp = dbc + l0 * 40;
  for (int li = 0; li < CHUNK; ++li) {
    float acc = bdt_v;
#pragma unroll
    for (int j = 0; j < 8; ++j)
      acc = fmaf(rp[li * 40 + j], wdt[j], acc);
    float dv = softplus_f(acc);
    float uv = up[(size_t)li * 256];
    float t = dv * uv;
#pragma unroll
    for (int n = 0; n < 16; ++n) {
      float dA = __expf(dv * Ac[n]);
      h[n] = fmaf(dA, h[n], t * rp[li * 40 + 8 + n]);
      Ap[n] *= dA;
    }
  }
  float4* cA = (float4*)(carryA + ((size_t)bid * 256 + d) * 16);
  float4* cH = (float4*)(carryH + ((size_t)bid * 256 + d) * 16);
#pragma unroll
  for (int q = 0; q < 4; ++q) {
    cA[q] = make_float4(Ap[q * 4], Ap[q * 4 + 1], Ap[q * 4 + 2], Ap[q * 4 + 3]);
    cH[q] = make_float4(h[q * 4], h[q * 4 + 1], h[q * 4 + 2], h[q * 4 + 3]);
  }
}

__global__ __launch_bounds__(256) void scan_mid(
    const float* __restrict__ carryA, float* __restrict__ carryH) {
  int gid = blockIdx.x * 256 + threadIdx.x;  // 16384 chains
  int b = gid >> 12;
  int dn = gid & 4095;
  float h = 0.f;
  for (int c = 0; c < NC; ++c) {
    size_t i = ((size_t)(b * NC + c) << 12) + dn;
    float a = carryA[i];
    float hl = carryH[i];
    carryH[i] = h;                 // h entering chunk c
    h = fmaf(a, h, hl);
  }
}

__global__ __launch_bounds__(256) void scan_pass3(
    const float* __restrict__ u, const float* __restrict__ dbc,
    const float* __restrict__ xz, const float* __restrict__ A_log,
    const float* __restrict__ Wdt, const float* __restrict__ bdt,
    const float* __restrict__ Dp, const float* __restrict__ carryH,
    float* __restrict__ y) {
  int bid = blockIdx.x;
  int b = bid >> 7;
  int c = bid & (NC - 1);
  int d = threadIdx.x;
  float Ac[16];
  {
    const float4* ar = (const float4*)(A_log + d * 16);
#pragma unroll
    for (int q = 0; q < 4; ++q) {
      float4 v = ar[q];
      Ac[q * 4 + 0] = -__expf(v.x); Ac[q * 4 + 1] = -__expf(v.y);
      Ac[q * 4 + 2] = -__expf(v.z); Ac[q * 4 + 3] = -__expf(v.w);
    }
  }
  float wdt[8];
  {
    const float4* wr = (const float4*)(Wdt + d * 8);
    float4 v0 = wr[0], v1 = wr[1];
    wdt[0] = v0.x; wdt[1] = v0.y; wdt[2] = v0.z; wdt[3] = v0.w;
    wdt[4] = v1.x; wdt[5] = v1.y; wdt[6] = v1.z; wdt[7] = v1.w;
  }
  float bdt_v = bdt[d];
  float Dv = Dp[d];
  float h[16];
  {
    const float4* cH = (const float4*)(carryH + ((size_t)bid * 256 + d) * 16);
#pragma unroll
    for (int q = 0; q < 4; ++q) {
      float4 v = cH[q];
      h[q * 4 + 0] = v.x; h[q * 4 + 1] = v.y;
      h[q * 4 + 2] = v.z; h[q * 4 + 3] = v.w;
    }
  }
  size_t l0 = (size_t)b * L_SEQ + (size_t)c * CHUNK;
  const float* up = u + l0 * 256 + d;
  const float* zp = xz + l0 * 512 + 256 + d;
  const float* rp = dbc + l0 * 40;
  float* yp = y + l0 * 256 + d;
  for (int li = 0; li < CHUNK; ++li) {
    float acc = bdt_v;
#pragma unroll
    for (int j = 0; j < 8; ++j)
      acc = fmaf(rp[li * 40 + j], wdt[j], acc);
    float dv = softplus_f(acc);
    float uv = up[(size_t)li * 256];
    float zv = zp[(size_t)li * 512];
    float t = dv * uv;
    float p = 0.f;
#pragma unroll
    for (int n = 0; n < 16; ++n) {
      float dA = __expf(dv * Ac[n]);
      h[n] = fmaf(dA, h[n], t * rp[li * 40 + 8 + n]);
      p = fmaf(h[n], rp[li * 40 + 24 + n], p);
    }
    float s = zv / (1.f + __expf(-zv));
    yp[(size_t)li * 256] = (p + uv * Dv) * s;
  }
}

// ---------------- K6: LayerNorm(ch) + silu + 1x1 conv -> out (B,64,H2,W2)
// 64 rows/block, grid (256, 2): blockIdx.y picks 32 of 64 output channels so
// each wave's Wo reads are wave-uniform (s_load scalar operands). LN stats
// computed once (4 threads/row + shfl), transform applied in-place in LDS.
__global__ __launch_bounds__(256) void ln_out_kernel(
    const float* __restrict__ s2, const float* __restrict__ gamma,
    const float* __restrict__ beta, const float* __restrict__ Wo,
    const float* __restrict__ bo, float* __restrict__ out) {
  __shared__ float xt[64][129];
  __shared__ float mus[64], invs[64];
  int tid = threadIdx.x;
  int m0 = blockIdx.x * 64;
  // Phase A: coalesced tile load -> LDS
  for (int i = 0; i < 8; ++i) {
    int s = tid + i * 256;          // 2048 float4 slots
    int r = s >> 5, q = s & 31;
    float4 v = *(const float4*)(s2 + (size_t)(m0 + r) * 128 + q * 4);
    xt[r][q * 4 + 0] = v.x; xt[r][q * 4 + 1] = v.y;
    xt[r][q * 4 + 2] = v.z; xt[r][q * 4 + 3] = v.w;
  }
  __syncthreads();
  // Phase B: stats, 4 threads per row
  {
    int r = tid >> 2, kq = (tid & 3) * 32;
    float s = 0.f, q = 0.f;
#pragma unroll 8
    for (int kk = 0; kk < 32; ++kk) {
      float v = xt[r][kq + kk];
      s += v; q = fmaf(v, v, q);
    }
    s += __shfl_xor(s, 1, 64); s += __shfl_xor(s, 2, 64);
    q += __shfl_xor(q, 1, 64); q += __shfl_xor(q, 2, 64);
    if ((tid & 3) == 0) {
      float mu = s * (1.f / 128.f);
      float var = q * (1.f / 128.f) - mu * mu;
      mus[r] = mu;
      invs[r] = rsqrtf(var + 1e-5f);
    }
  }
  __syncthreads();
  // Phase T: LN + silu in-place
  for (int i = 0; i < 32; ++i) {
    int idx = tid + i * 256;        // 8192 elements
    int r = idx >> 7, k = idx & 127;
    float v = xt[r][k];
    float xn = (v - mus[r]) * invs[r] * gamma[k] + beta[k];
    xt[r][k] = xn / (1.f + __expf(-xn));
  }
  __syncthreads();
  // Phase C: GEMM, lane = row, wave-uniform channels
  int lane = tid & 63;
  int w = __builtin_amdgcn_readfirstlane(tid >> 6);
  int cbase = blockIdx.y * 32 + w * 8;
  const float* Wrow = Wo + cbase * 128;
  float acc[8];
#pragma unroll
  for (int j = 0; j < 8; ++j) acc[j] = 0.f;
#pragma unroll 4
  for (int k = 0; k < 128; ++k) {
    float v = xt[lane][k];
#pragma unroll
    for (int j = 0; j < 8; ++j)
      acc[j] = fmaf(v, Wrow[j * 128 + k], acc[j]);
  }
  int m = m0 + lane;
  int b = m >> 12, l = m & 4095;
#pragma unroll
  for (int j = 0; j < 8; ++j)
    out[((size_t)b * 64 + cbase + j) * 4096 + l] = acc[j] + bo[cbase + j];
}

extern "C" void kernel_launch(void* const* d_in, const int* in_sizes, int n_in,
                              void* d_out, int out_size, void* d_ws, size_t ws_size,
                              hipStream_t stream) {
  (void)in_sizes; (void)n_in; (void)out_size; (void)ws_size;
  const float* x         = (const float*)d_in[0];
  const float* skip      = (const float*)d_in[1];
  const float* up_w      = (const float*)d_in[2];
  const float* up_b      = (const float*)d_in[3];
  const float* in_proj_w = (const float*)d_in[4];
  const float* conv1d_w  = (const float*)d_in[5];
  const float* conv1d_b  = (const float*)d_in[6];
  const float* x_proj_w  = (const float*)d_in[7];
  const float* dt_proj_w = (const float*)d_in[8];
  const float* dt_proj_b = (const float*)d_in[9];
  const float* A_log     = (const float*)d_in[10];
  const float* Dp        = (const float*)d_in[11];
  const float* out_proj_w= (const float*)d_in[12];
  const float* ln_gamma  = (const float*)d_in[13];
  const float* ln_beta   = (const float*)d_in[14];
  const float* convout_w = (const float*)d_in[15];
  const float* convout_b = (const float*)d_in[16];
  float* out = (float*)d_out;
  float* ws  = (float*)d_ws;

  // workspace layout (floats)
  float* seq    = ws;                  // 2,097,152  (reused as s2 after out_proj)
  float* xz     = ws + 2097152;        // 8,388,608
  float* u      = ws + 10485760;       // 4,194,304
  float* dbc    = ws + 14680064;       //   655,360
  float* y      = ws + 15335424;       // 4,194,304
  float* carryA = ws + 19529728;       // 2,097,152  (= 4*NC*256*16)
  float* carryH = ws + 21626880;       // 2,097,152

  upcat_kernel<<<256, 256, 0, stream>>>(x, skip, up_w, up_b, seq);
  gemm_bt<<<dim3(16384 / 64, 512 / 64), 256, 0, stream>>>(seq, in_proj_w, xz,
                                                          16384, 512, 128);
  conv_silu_kernel<<<16384, 256, 0, stream>>>(xz, conv1d_w, conv1d_b, u);
  xproj_kernel<<<16384 / 64, 256, 0, stream>>>(u, x_proj_w, dbc);
  scan_pass1<<<4 * NC, 256, 0, stream>>>(u, dbc, A_log, dt_proj_w, dt_proj_b,
                                         carryA, carryH);
  scan_mid<<<64, 256, 0, stream>>>(carryA, carryH);
  scan_pass3<<<4 * NC, 256, 0, stream>>>(u, dbc, xz, A_log, dt_proj_w,
                                         dt_proj_b, Dp, carryH, y);
  gemm_bt<<<dim3(16384 / 64, 128 / 64), 256, 0, stream>>>(y, out_proj_w, seq,
                                                          16384, 128, 256);
  ln_out_kernel<<<dim3(256, 2), 256, 0, stream>>>(seq, ln_gamma, ln_beta,
                                                  convout_w, convout_b, out);
}